// Round 7
// baseline (4498.583 us; speedup 1.0000x reference)
//
#include <hip/hip_runtime.h>
#include <hip/hip_bf16.h>

#define B_   2048
#define V_   1024
#define H_   512
#define E_   256
#define L_   32

typedef __attribute__((ext_vector_type(4))) float f32x4;
typedef __attribute__((ext_vector_type(2))) long i64x2;
typedef unsigned short u16;
typedef unsigned int   u32;
typedef unsigned char  u8;
typedef long long      i64;

// OCP e4m3fn encode, RNE, flush below 2^-6 (callers pre-scale so this is negligible)
__device__ __forceinline__ u8 f2e4m3(float x) {
    union { float f; u32 u; } v; v.f = x;
    u32 s = (v.u >> 24) & 0x80u;
    u32 a = v.u & 0x7fffffffu;
    if (a < 0x3c800000u) return (u8)s;            // |x| < 2^-6 -> 0
    if (a > 0x43e00000u) a = 0x43e00000u;         // clamp 448
    u32 r = a + 0x000fffffu + ((a >> 20) & 1u);   // RNE to 3-bit mantissa
    if (r > 0x43e00000u) r = 0x43e00000u;
    u32 ex = (r >> 23) - 120u;
    u32 mn = (r >> 20) & 7u;
    return (u8)(s | (ex << 3) | mn);
}
// fast single-value fp8 encode via HW packer when available
__device__ __forceinline__ u8 f2fp8(float x) {
#if __has_builtin(__builtin_amdgcn_cvt_pk_fp8_f32)
    return (u8)(__builtin_amdgcn_cvt_pk_fp8_f32(x, x, 0, false) & 0xff);
#else
    return f2e4m3(x);
#endif
}
__device__ __forceinline__ float sig_(float x)  { return 1.f / (1.f + __expf(-x)); }
__device__ __forceinline__ float tanh_(float x) { return 1.f - 2.f / (__expf(2.f * x) + 1.f); }

// -------------------------------------------------------------------------
// Weight layouts (per-wave VGPR-ring order), all fp8 e4m3 scaled x64.
// Unit = 16 KB = 8 waves x 2 KB; a wave's 2 KB = 2 x dwordx4/lane (1 KB apart),
// each dwordx4 = 2 fragments: lane l gets frag(2p)[l] in .xy, frag(2p+1)[l] in .zw
// w1f: [u=ks*4+g 96][wv 8][p 2][l 64][j2 2][e 8]
//      k = ks*32+(l>>4)*8+e,  n = g*512 + wv*64 + (2p+j2)*16 + (l&15)
// wof: [u=ks*2+hf 32][wv 8][p 2][l 64][j2 2][e 8]
//      k = ks*32+(l>>4)*8+e,  v = wv*128 + hf*64 + (2p+j2)*16 + (l&15)
// wef: [ksp 16][wv 8][s 2][l 64][j2 2][e 8]
//      k = (2*ksp+s)*32+(l>>4)*8+e,  col = wv*32 + j2*16 + (l&15)
// b1 = b_ih + b_hh (fp32)
// -------------------------------------------------------------------------
__global__ void prep(const float* __restrict__ W_ih, const float* __restrict__ W_hh,
                     const float* __restrict__ b_ih, const float* __restrict__ b_hh,
                     const float* __restrict__ W_out, const float* __restrict__ W_emb,
                     u8* __restrict__ w1f, u8* __restrict__ wof, u8* __restrict__ wef,
                     float* __restrict__ b1)
{
    int idx = blockIdx.x * 256 + threadIdx.x;
    if (idx < 1572864) {                       // W1 = [W_ih | W_hh] -> fp8*64
        int e = idx & 7, j2 = (idx >> 3) & 1, l = (idx >> 4) & 63, p = (idx >> 10) & 1,
            wv = (idx >> 11) & 7, g = (idx >> 14) & 3, ks = idx >> 16;
        int k = ks * 32 + ((l >> 4) << 3) + e;
        int n = g * 512 + wv * 64 + (2 * p + j2) * 16 + (l & 15);
        float v = (k < E_) ? W_ih[n * E_ + k] : W_hh[n * H_ + (k - E_)];
        w1f[idx] = f2e4m3(v * 64.f);
    } else if (idx < 2097152) {                // W_out -> fp8*64
        int j = idx - 1572864;
        int e = j & 7, j2 = (j >> 3) & 1, l = (j >> 4) & 63, p = (j >> 10) & 1,
            wv = (j >> 11) & 7, hf = (j >> 14) & 1, ks = j >> 15;
        int k = ks * 32 + ((l >> 4) << 3) + e;
        int v = wv * 128 + hf * 64 + (2 * p + j2) * 16 + (l & 15);
        wof[j] = f2e4m3(W_out[v * H_ + k] * 64.f);
    } else if (idx < 2359296) {                // W_emb -> fp8*64
        int j = idx - 2097152;
        int e = j & 7, j2 = (j >> 3) & 1, l = (j >> 4) & 63, s = (j >> 10) & 1,
            wv = (j >> 11) & 7, ksp = j >> 14;
        int k = (2 * ksp + s) * 32 + ((l >> 4) << 3) + e;
        int ce = wv * 32 + j2 * 16 + (l & 15);
        wef[j] = f2e4m3(W_emb[ce * V_ + k] * 64.f);
    } else if (idx < 2361344) {
        int j = idx - 2359296;
        b1[j] = b_ih[j] + b_hh[j];
    }
}

// LDS layout (bytes) — activations + reductions only; weights go L2 -> VGPR
#define AEO   0u        // 16 x 776 fp8: [0,256) e*16, [256,768) h*16
#define XSO   12416u    // 16 x 1040 fp8 xs = exp(z-m)*256
#define RMX   29056u    // 16x8 f32 row-max partials (1 KB slot)
#define RSM   30080u    // 16x8 f32 row-sum partials (1 KB slot)
#define LDS_TOTAL 31104

__global__ __launch_bounds__(512, 1)
void lstm_fused(const float* __restrict__ x, const float* __restrict__ gum,
                const u8* __restrict__ w1f, const u8* __restrict__ wof,
                const u8* __restrict__ wef, const float* __restrict__ b1,
                const float* __restrict__ b_out, const float* __restrict__ b_emb,
                const float* __restrict__ sos, float* __restrict__ out)
{
    __shared__ __align__(16) char smem[LDS_TOTAL];

    const u32 tid = threadIdx.x;
    const u32 w   = tid >> 6;        // wave 0..7
    const u32 l   = tid & 63u;
    const u32 q   = l >> 4;
    const u32 col = l & 15u;
    const int r0  = blockIdx.x << 4;

    const u32 q8  = q << 3;
    const u32 colB776  = col * 776u;
    const u32 colB1040 = col * 1040u;

    // per-wave/lane weight base pointers (wave slice = wv*2048 + l*16 inside a unit)
    const char* w1base = (const char*)w1f + (w << 11) + (l << 4);
    const char* wobase = (const char*)wof + (w << 11) + (l << 4);
    const char* webase = (const char*)wef + (w << 11) + (l << 4);

    // EOS row (nontemporal stream)
    for (u32 i = tid; i < 16 * V_; i += 512) {
        u32 b = i >> 10, v = i & (V_ - 1);
        __builtin_nontemporal_store((v == 0) ? 1.f : 0.f,
                                    &out[((size_t)(r0 + b) * 33 + 32) * V_ + v]);
    }
    // e0 = sos*16 (fp8), h0 = x*16 (fp8)
    for (u32 i = tid; i < 16 * E_; i += 512) {
        u32 b = i >> 8, k = i & (E_ - 1);
        *(u8*)(smem + AEO + b * 776u + k) = f2fp8(sos[k] * 16.f);
    }
    for (u32 i = tid; i < 16 * H_; i += 512) {
        u32 b = i >> 9, k = i & (H_ - 1);
        *(u8*)(smem + AEO + b * 776u + 256u + k) = f2fp8(x[(r0 + b) * H_ + k] * 16.f);
    }

    // hoisted biases: wave owns j in [64w, 64w+64)
    float bia[4], bfa[4], bga[4], boa[4];
    #pragma unroll
    for (int jj = 0; jj < 4; ++jj) {
        int j = (w << 6) + (jj << 4) + col;
        bia[jj] = b1[j];           bfa[jj] = b1[H_ + j];
        bga[jj] = b1[2 * H_ + j];  boa[jj] = b1[3 * H_ + j];
    }
    float bov[2][4];
    #pragma unroll
    for (int hf = 0; hf < 2; ++hf)
        #pragma unroll
        for (int jj = 0; jj < 4; ++jj)
            bov[hf][jj] = b_out[(w << 7) + (hf << 6) + (jj << 4) + col];
    float bem16[2];
    #pragma unroll
    for (int jj = 0; jj < 2; ++jj)
        bem16[jj] = b_emb[(w << 5) + (jj << 4) + col] * 16.f;

    float creg[4][4];
    #pragma unroll
    for (int jj = 0; jj < 4; ++jj)
        #pragma unroll
        for (int r = 0; r < 4; ++r) creg[jj][r] = 0.f;

    __syncthreads();

    const f32x4 fz = {0.f, 0.f, 0.f, 0.f};
    const float S1 = 1.f / 1024.f;            // 1/(A_SC*W_SC) = 1/(16*64)

    #pragma unroll 1
    for (int t = 0; t < L_; ++t) {
        // ====== phase A: gates, VGPR ring depth 8 (96 units x 2 KB/wave) ======
        f32x4 acc[4][4];
        #pragma unroll
        for (int g = 0; g < 4; ++g)
            #pragma unroll
            for (int jj = 0; jj < 4; ++jj) acc[g][jj] = fz;

        i64x2 rA[8][2];
#define LDA(U, S) { const char* _p = w1base + (size_t)(U) * 16384; \
        rA[S][0] = *(const i64x2*)_p; rA[S][1] = *(const i64x2*)(_p + 1024); }
        LDA(0, 0); LDA(1, 1); LDA(2, 2); LDA(3, 3);
        LDA(4, 4); LDA(5, 5); LDA(6, 6); LDA(7, 7);
        #pragma unroll
        for (int ks = 0; ks < 24; ++ks) {
            i64 a8 = *(const i64*)(smem + AEO + colB776 + ((u32)ks << 5) + q8);
            #pragma unroll
            for (int g = 0; g < 4; ++g) {
                const int u = ks * 4 + g, s = u & 7;
                acc[g][0] = __builtin_amdgcn_mfma_f32_16x16x32_fp8_fp8(a8, rA[s][0][0], acc[g][0], 0, 0, 0);
                acc[g][1] = __builtin_amdgcn_mfma_f32_16x16x32_fp8_fp8(a8, rA[s][0][1], acc[g][1], 0, 0, 0);
                acc[g][2] = __builtin_amdgcn_mfma_f32_16x16x32_fp8_fp8(a8, rA[s][1][0], acc[g][2], 0, 0, 0);
                acc[g][3] = __builtin_amdgcn_mfma_f32_16x16x32_fp8_fp8(a8, rA[s][1][1], acc[g][3], 0, 0, 0);
                if (u + 8 < 96) LDA(u + 8, s);
            }
        }
#undef LDA
        __syncthreads();            // all AEO reads done before h overwrite

        #pragma unroll
        for (int jj = 0; jj < 4; ++jj) {
            int j = (w << 6) + (jj << 4) + col;
            #pragma unroll
            for (int r = 0; r < 4; ++r) {
                float gi = sig_(acc[0][jj][r] * S1 + bia[jj]);
                float gf = sig_(acc[1][jj][r] * S1 + bfa[jj]);
                float gg = tanh_(acc[2][jj][r] * S1 + bga[jj]);
                float go = sig_(acc[3][jj][r] * S1 + boa[jj]);
                float c  = gf * creg[jj][r] + gi * gg;
                creg[jj][r] = c;
                float h = go * tanh_(c);
                *(u8*)(smem + AEO + ((q << 2) + r) * 776u + 256u + (u32)j) = f2fp8(h * 16.f);
            }
        }
        __syncthreads();            // h complete

        // ====== phase B: logits, VGPR ring depth 8 (32 units) + softmax ======
        f32x4 accB[2][4];
        #pragma unroll
        for (int hf = 0; hf < 2; ++hf)
            #pragma unroll
            for (int jj = 0; jj < 4; ++jj) accB[hf][jj] = fz;

        i64x2 rB[8][2];
#define LDB(U, S) { const char* _p = wobase + (size_t)(U) * 16384; \
        rB[S][0] = *(const i64x2*)_p; rB[S][1] = *(const i64x2*)(_p + 1024); }
        LDB(0, 0); LDB(1, 1); LDB(2, 2); LDB(3, 3);
        LDB(4, 4); LDB(5, 5); LDB(6, 6); LDB(7, 7);

        // gumbel prefetch AFTER ring prologue (ring waits never imply gr)
        const float* gt = gum + (size_t)t * (B_ * V_) + (size_t)r0 * V_;
        f32x4 gr[2][4];
        #pragma unroll
        for (int hf = 0; hf < 2; ++hf)
            #pragma unroll
            for (int jj = 0; jj < 4; ++jj) {
                int v = (w << 7) + (hf << 6) + (jj << 4) + col;
                #pragma unroll
                for (int r = 0; r < 4; ++r)
                    gr[hf][jj][r] = __builtin_nontemporal_load(&gt[((q << 2) + r) * V_ + v]);
            }

        #pragma unroll
        for (int ks = 0; ks < 16; ++ks) {
            i64 a8 = *(const i64*)(smem + AEO + colB776 + 256u + ((u32)ks << 5) + q8);
            #pragma unroll
            for (int hf = 0; hf < 2; ++hf) {
                const int u = ks * 2 + hf, s = u & 7;
                accB[hf][0] = __builtin_amdgcn_mfma_f32_16x16x32_fp8_fp8(a8, rB[s][0][0], accB[hf][0], 0, 0, 0);
                accB[hf][1] = __builtin_amdgcn_mfma_f32_16x16x32_fp8_fp8(a8, rB[s][0][1], accB[hf][1], 0, 0, 0);
                accB[hf][2] = __builtin_amdgcn_mfma_f32_16x16x32_fp8_fp8(a8, rB[s][1][0], accB[hf][2], 0, 0, 0);
                accB[hf][3] = __builtin_amdgcn_mfma_f32_16x16x32_fp8_fp8(a8, rB[s][1][1], accB[hf][3], 0, 0, 0);
                if (u + 8 < 32) LDB(u + 8, s);
            }
        }
#undef LDB

        // z = acc*S1 + bias + gumbel (in place); row-max
        float mx[4];
        #pragma unroll
        for (int r = 0; r < 4; ++r) mx[r] = -1e30f;
        #pragma unroll
        for (int hf = 0; hf < 2; ++hf)
            #pragma unroll
            for (int jj = 0; jj < 4; ++jj)
                #pragma unroll
                for (int r = 0; r < 4; ++r) {
                    float zz = accB[hf][jj][r] * S1 + bov[hf][jj] + gr[hf][jj][r];
                    accB[hf][jj][r] = zz;
                    mx[r] = fmaxf(mx[r], zz);
                }
        #pragma unroll
        for (int m = 1; m < 16; m <<= 1)
            #pragma unroll
            for (int r = 0; r < 4; ++r) mx[r] = fmaxf(mx[r], __shfl_xor(mx[r], m, 64));
        if (col == 0) {
            #pragma unroll
            for (int r = 0; r < 4; ++r)
                *(float*)(smem + RMX + ((((q << 2) + r) << 3) + w) * 4u) = mx[r];
        }
        __syncthreads();
        float m_[4];
        #pragma unroll
        for (int r = 0; r < 4; ++r) {
            float mm = -1e30f;
            #pragma unroll
            for (int ww = 0; ww < 8; ++ww)
                mm = fmaxf(mm, *(const float*)(smem + RMX + ((((q << 2) + r) << 3) + ww) * 4u));
            m_[r] = mm;
        }
        // eb = exp(z - m) in place; row-sum; stage xs = eb*256 fp8
        float ps[4] = {0.f, 0.f, 0.f, 0.f};
        #pragma unroll
        for (int hf = 0; hf < 2; ++hf)
            #pragma unroll
            for (int jj = 0; jj < 4; ++jj) {
                u32 v = (w << 7) + (hf << 6) + (jj << 4) + col;
                #pragma unroll
                for (int r = 0; r < 4; ++r) {
                    float Ee = __expf(accB[hf][jj][r] - m_[r]);
                    accB[hf][jj][r] = Ee;
                    ps[r] += Ee;
                    *(u8*)(smem + XSO + ((q << 2) + r) * 1040u + v) = f2fp8(Ee * 256.f);
                }
            }
        #pragma unroll
        for (int m = 1; m < 16; m <<= 1)
            #pragma unroll
            for (int r = 0; r < 4; ++r) ps[r] += __shfl_xor(ps[r], m, 64);
        if (col == 0) {
            #pragma unroll
            for (int r = 0; r < 4; ++r)
                *(float*)(smem + RSM + ((((q << 2) + r) << 3) + w) * 4u) = ps[r];
        }
        __syncthreads();
        float invs[4];
        #pragma unroll
        for (int r = 0; r < 4; ++r) {
            float s = 0.f;
            #pragma unroll
            for (int ww = 0; ww < 8; ++ww)
                s += *(const float*)(smem + RSM + ((((q << 2) + r) << 3) + ww) * 4u);
            invs[r] = 1.f / s;
        }

        // ====== phase C prologue loads BEFORE out-stores (ring waits never imply stores) ======
        f32x4 accC[2];
        accC[0] = fz; accC[1] = fz;
        i64x2 rC[4][2];
#define LDC(U, S) { const char* _p = webase + (size_t)(U) * 16384; \
        rC[S][0] = *(const i64x2*)_p; rC[S][1] = *(const i64x2*)(_p + 1024); }
        LDC(0, 0); LDC(1, 1); LDC(2, 2); LDC(3, 3);

        // normalized softmax out (fp32, nontemporal stream)
        #pragma unroll
        for (int hf = 0; hf < 2; ++hf)
            #pragma unroll
            for (int jj = 0; jj < 4; ++jj) {
                int v = (w << 7) + (hf << 6) + (jj << 4) + col;
                #pragma unroll
                for (int r = 0; r < 4; ++r) {
                    int b = (q << 2) + r;
                    __builtin_nontemporal_store(accB[hf][jj][r] * invs[r],
                        &out[((size_t)(r0 + b) * 33 + t) * V_ + v]);
                }
            }

        // ====== phase C: e_new, VGPR ring depth 4 (16 units) ======
        #pragma unroll
        for (int ksp = 0; ksp < 16; ++ksp) {
            const int s = ksp & 3;
            i64 x0 = *(const i64*)(smem + XSO + colB1040 + ((u32)ksp << 6) + q8);
            i64 x1 = *(const i64*)(smem + XSO + colB1040 + ((u32)ksp << 6) + 32u + q8);
            accC[0] = __builtin_amdgcn_mfma_f32_16x16x32_fp8_fp8(x0, rC[s][0][0], accC[0], 0, 0, 0);
            accC[1] = __builtin_amdgcn_mfma_f32_16x16x32_fp8_fp8(x0, rC[s][0][1], accC[1], 0, 0, 0);
            accC[0] = __builtin_amdgcn_mfma_f32_16x16x32_fp8_fp8(x1, rC[s][1][0], accC[0], 0, 0, 0);
            accC[1] = __builtin_amdgcn_mfma_f32_16x16x32_fp8_fp8(x1, rC[s][1][1], accC[1], 0, 0, 0);
            if (ksp + 4 < 16) LDC(ksp + 4, s);
        }
#undef LDC

        {   // e = accC*invs/(256*64) + b_emb ; store e*16 as fp8
            #pragma unroll
            for (int jj = 0; jj < 2; ++jj) {
                u32 ce = (w << 5) + (jj << 4) + col;
                #pragma unroll
                for (int r = 0; r < 4; ++r) {
                    float e_ = accC[jj][r] * invs[r] * (16.f / 16384.f) + bem16[jj];
                    *(u8*)(smem + AEO + ((q << 2) + r) * 776u + ce) = f2fp8(e_);
                }
            }
        }
        __syncthreads();            // e complete before next step's phase A
    }
}

extern "C" void kernel_launch(void* const* d_in, const int* in_sizes, int n_in,
                              void* d_out, int out_size, void* d_ws, size_t ws_size,
                              hipStream_t stream) {
    const float* x     = (const float*)d_in[0];
    const float* gum   = (const float*)d_in[1];
    const float* W_ih  = (const float*)d_in[2];
    const float* W_hh  = (const float*)d_in[3];
    const float* b_ih  = (const float*)d_in[4];
    const float* b_hh  = (const float*)d_in[5];
    const float* W_out = (const float*)d_in[6];
    const float* b_out = (const float*)d_in[7];
    const float* W_emb = (const float*)d_in[8];
    const float* b_emb = (const float*)d_in[9];
    const float* sos   = (const float*)d_in[10];
    float* out = (float*)d_out;

    char* ws = (char*)d_ws;
    u8*    w1f = (u8*)(ws);                    // 1,572,864 B (fp8)
    u8*    wof = (u8*)(ws + 1572864);          //   524,288 B (fp8)
    u8*    wef = (u8*)(ws + 2097152);          //   262,144 B (fp8)
    float* b1  = (float*)(ws + 2359296);       //     8,192 B

    prep<<<9224, 256, 0, stream>>>(W_ih, W_hh, b_ih, b_hh, W_out, W_emb,
                                   w1f, wof, wef, b1);
    lstm_fused<<<128, 512, 0, stream>>>(x, gum, w1f, wof, wef, b1,
                                        b_out, b_emb, sos, out);
}

// Round 8
// 4334.774 us; speedup vs baseline: 1.0378x; 1.0378x over previous
//
#include <hip/hip_runtime.h>
#include <hip/hip_bf16.h>

#define B_   2048
#define V_   1024
#define H_   512
#define E_   256
#define L_   32

typedef __attribute__((ext_vector_type(4))) float f32x4;
typedef __attribute__((ext_vector_type(2))) long i64x2;
typedef unsigned short u16;
typedef unsigned int   u32;
typedef unsigned char  u8;
typedef long long      i64;

// OCP e4m3fn encode, RNE, flush below 2^-6 (callers pre-scale so this is negligible)
__device__ __forceinline__ u8 f2e4m3(float x) {
    union { float f; u32 u; } v; v.f = x;
    u32 s = (v.u >> 24) & 0x80u;
    u32 a = v.u & 0x7fffffffu;
    if (a < 0x3c800000u) return (u8)s;            // |x| < 2^-6 -> 0
    if (a > 0x43e00000u) a = 0x43e00000u;         // clamp 448
    u32 r = a + 0x000fffffu + ((a >> 20) & 1u);   // RNE to 3-bit mantissa
    if (r > 0x43e00000u) r = 0x43e00000u;
    u32 ex = (r >> 23) - 120u;
    u32 mn = (r >> 20) & 7u;
    return (u8)(s | (ex << 3) | mn);
}
// fast single-value fp8 encode via HW packer when available
__device__ __forceinline__ u8 f2fp8(float x) {
#if __has_builtin(__builtin_amdgcn_cvt_pk_fp8_f32)
    return (u8)(__builtin_amdgcn_cvt_pk_fp8_f32(x, x, 0, false) & 0xff);
#else
    return f2e4m3(x);
#endif
}
__device__ __forceinline__ float sig_(float x)  { return 1.f / (1.f + __expf(-x)); }
__device__ __forceinline__ float tanh_(float x) { return 1.f - 2.f / (__expf(2.f * x) + 1.f); }

// -------------------------------------------------------------------------
// Weight layouts (per-wave VGPR-ring order), all fp8 e4m3 scaled x64.
// Unit = 16 KB = 8 waves x 2 KB; a wave's 2 KB = 2 x dwordx4/lane (1 KB apart),
// each dwordx4 = 2 fragments: lane l gets frag(2p)[l] in .xy, frag(2p+1)[l] in .zw
// w1f: [u=ks*4+g 96][wv 8][p 2][l 64][j2 2][e 8]
//      k = ks*32+(l>>4)*8+e,  n = g*512 + wv*64 + (2p+j2)*16 + (l&15)
// wof: [u=ks*2+hf 32][wv 8][p 2][l 64][j2 2][e 8]
//      k = ks*32+(l>>4)*8+e,  v = wv*128 + hf*64 + (2p+j2)*16 + (l&15)
// wef: [ksp 16][wv 8][s 2][l 64][j2 2][e 8]
//      k = (2*ksp+s)*32+(l>>4)*8+e,  col = wv*32 + j2*16 + (l&15)
// b1 = b_ih + b_hh (fp32)
// -------------------------------------------------------------------------
__global__ void prep(const float* __restrict__ W_ih, const float* __restrict__ W_hh,
                     const float* __restrict__ b_ih, const float* __restrict__ b_hh,
                     const float* __restrict__ W_out, const float* __restrict__ W_emb,
                     u8* __restrict__ w1f, u8* __restrict__ wof, u8* __restrict__ wef,
                     float* __restrict__ b1)
{
    int idx = blockIdx.x * 256 + threadIdx.x;
    if (idx < 1572864) {                       // W1 = [W_ih | W_hh] -> fp8*64
        int e = idx & 7, j2 = (idx >> 3) & 1, l = (idx >> 4) & 63, p = (idx >> 10) & 1,
            wv = (idx >> 11) & 7, g = (idx >> 14) & 3, ks = idx >> 16;
        int k = ks * 32 + ((l >> 4) << 3) + e;
        int n = g * 512 + wv * 64 + (2 * p + j2) * 16 + (l & 15);
        float v = (k < E_) ? W_ih[n * E_ + k] : W_hh[n * H_ + (k - E_)];
        w1f[idx] = f2e4m3(v * 64.f);
    } else if (idx < 2097152) {                // W_out -> fp8*64
        int j = idx - 1572864;
        int e = j & 7, j2 = (j >> 3) & 1, l = (j >> 4) & 63, p = (j >> 10) & 1,
            wv = (j >> 11) & 7, hf = (j >> 14) & 1, ks = j >> 15;
        int k = ks * 32 + ((l >> 4) << 3) + e;
        int v = wv * 128 + hf * 64 + (2 * p + j2) * 16 + (l & 15);
        wof[j] = f2e4m3(W_out[v * H_ + k] * 64.f);
    } else if (idx < 2359296) {                // W_emb -> fp8*64
        int j = idx - 2097152;
        int e = j & 7, j2 = (j >> 3) & 1, l = (j >> 4) & 63, s = (j >> 10) & 1,
            wv = (j >> 11) & 7, ksp = j >> 14;
        int k = (2 * ksp + s) * 32 + ((l >> 4) << 3) + e;
        int ce = wv * 32 + j2 * 16 + (l & 15);
        wef[j] = f2e4m3(W_emb[ce * V_ + k] * 64.f);
    } else if (idx < 2361344) {
        int j = idx - 2359296;
        b1[j] = b_ih[j] + b_hh[j];
    }
}

// LDS layout (bytes) — activations + reductions only; weights go L2 -> VGPR
#define AEO   0u        // 16 x 776 fp8: [0,256) e*16, [256,768) h*16
#define XSO   12416u    // 16 x 1040 fp8 xs = exp(z-m)*256
#define RMX   29056u    // 16x8 f32 row-max partials (1 KB slot)
#define RSM   30080u    // 16x8 f32 row-sum partials (1 KB slot)
#define LDS_TOTAL 31104

// 512 threads = 8 waves = exactly 2 waves/EU; pin allocator to 2/EU so the
// VGPR budget is 512/2 = 256 (r5 proved waves_per_eu(4,4) -> 128 is honored).
__global__ __launch_bounds__(512)
__attribute__((amdgpu_waves_per_eu(2, 2)))
void lstm_fused(const float* __restrict__ x, const float* __restrict__ gum,
                const u8* __restrict__ w1f, const u8* __restrict__ wof,
                const u8* __restrict__ wef, const float* __restrict__ b1,
                const float* __restrict__ b_out, const float* __restrict__ b_emb,
                const float* __restrict__ sos, float* __restrict__ out)
{
    __shared__ __align__(16) char smem[LDS_TOTAL];

    const u32 tid = threadIdx.x;
    const u32 w   = tid >> 6;        // wave 0..7
    const u32 l   = tid & 63u;
    const u32 q   = l >> 4;
    const u32 col = l & 15u;
    const int r0  = blockIdx.x << 4;

    const u32 q8  = q << 3;
    const u32 colB776  = col * 776u;
    const u32 colB1040 = col * 1040u;

    // per-wave/lane weight base pointers (wave slice = wv*2048 + l*16 inside a unit)
    const char* w1base = (const char*)w1f + (w << 11) + (l << 4);
    const char* wobase = (const char*)wof + (w << 11) + (l << 4);
    const char* webase = (const char*)wef + (w << 11) + (l << 4);

    // EOS row (nontemporal stream)
    for (u32 i = tid; i < 16 * V_; i += 512) {
        u32 b = i >> 10, v = i & (V_ - 1);
        __builtin_nontemporal_store((v == 0) ? 1.f : 0.f,
                                    &out[((size_t)(r0 + b) * 33 + 32) * V_ + v]);
    }
    // e0 = sos*16 (fp8), h0 = x*16 (fp8)
    for (u32 i = tid; i < 16 * E_; i += 512) {
        u32 b = i >> 8, k = i & (E_ - 1);
        *(u8*)(smem + AEO + b * 776u + k) = f2fp8(sos[k] * 16.f);
    }
    for (u32 i = tid; i < 16 * H_; i += 512) {
        u32 b = i >> 9, k = i & (H_ - 1);
        *(u8*)(smem + AEO + b * 776u + 256u + k) = f2fp8(x[(r0 + b) * H_ + k] * 16.f);
    }

    // hoisted biases: wave owns j in [64w, 64w+64)
    float bia[4], bfa[4], bga[4], boa[4];
    #pragma unroll
    for (int jj = 0; jj < 4; ++jj) {
        int j = (w << 6) + (jj << 4) + col;
        bia[jj] = b1[j];           bfa[jj] = b1[H_ + j];
        bga[jj] = b1[2 * H_ + j];  boa[jj] = b1[3 * H_ + j];
    }
    float bov[2][4];
    #pragma unroll
    for (int hf = 0; hf < 2; ++hf)
        #pragma unroll
        for (int jj = 0; jj < 4; ++jj)
            bov[hf][jj] = b_out[(w << 7) + (hf << 6) + (jj << 4) + col];
    float bem16[2];
    #pragma unroll
    for (int jj = 0; jj < 2; ++jj)
        bem16[jj] = b_emb[(w << 5) + (jj << 4) + col] * 16.f;

    float creg[4][4];
    #pragma unroll
    for (int jj = 0; jj < 4; ++jj)
        #pragma unroll
        for (int r = 0; r < 4; ++r) creg[jj][r] = 0.f;

    __syncthreads();

    const f32x4 fz = {0.f, 0.f, 0.f, 0.f};
    const float S1 = 1.f / 1024.f;            // 1/(A_SC*W_SC) = 1/(16*64)

    #pragma unroll 1
    for (int t = 0; t < L_; ++t) {
        // ====== phase A: gates, VGPR ring depth 8 (96 units x 2 KB/wave) ======
        f32x4 acc[4][4];
        #pragma unroll
        for (int g = 0; g < 4; ++g)
            #pragma unroll
            for (int jj = 0; jj < 4; ++jj) acc[g][jj] = fz;

        i64x2 rA[8][2];
#define LDA(U, S) { const char* _p = w1base + (size_t)(U) * 16384; \
        rA[S][0] = *(const i64x2*)_p; rA[S][1] = *(const i64x2*)(_p + 1024); }
        LDA(0, 0); LDA(1, 1); LDA(2, 2); LDA(3, 3);
        LDA(4, 4); LDA(5, 5); LDA(6, 6); LDA(7, 7);
        #pragma unroll
        for (int ks = 0; ks < 24; ++ks) {
            i64 a8 = *(const i64*)(smem + AEO + colB776 + ((u32)ks << 5) + q8);
            #pragma unroll
            for (int g = 0; g < 4; ++g) {
                const int u = ks * 4 + g, s = u & 7;
                acc[g][0] = __builtin_amdgcn_mfma_f32_16x16x32_fp8_fp8(a8, rA[s][0][0], acc[g][0], 0, 0, 0);
                acc[g][1] = __builtin_amdgcn_mfma_f32_16x16x32_fp8_fp8(a8, rA[s][0][1], acc[g][1], 0, 0, 0);
                acc[g][2] = __builtin_amdgcn_mfma_f32_16x16x32_fp8_fp8(a8, rA[s][1][0], acc[g][2], 0, 0, 0);
                acc[g][3] = __builtin_amdgcn_mfma_f32_16x16x32_fp8_fp8(a8, rA[s][1][1], acc[g][3], 0, 0, 0);
                if (u + 8 < 96) LDA(u + 8, s);
            }
        }
#undef LDA
        __syncthreads();            // all AEO reads done before h overwrite

        #pragma unroll
        for (int jj = 0; jj < 4; ++jj) {
            int j = (w << 6) + (jj << 4) + col;
            #pragma unroll
            for (int r = 0; r < 4; ++r) {
                float gi = sig_(acc[0][jj][r] * S1 + bia[jj]);
                float gf = sig_(acc[1][jj][r] * S1 + bfa[jj]);
                float gg = tanh_(acc[2][jj][r] * S1 + bga[jj]);
                float go = sig_(acc[3][jj][r] * S1 + boa[jj]);
                float c  = gf * creg[jj][r] + gi * gg;
                creg[jj][r] = c;
                float h = go * tanh_(c);
                *(u8*)(smem + AEO + ((q << 2) + r) * 776u + 256u + (u32)j) = f2fp8(h * 16.f);
            }
        }
        __syncthreads();            // h complete

        // ====== phase B: logits, VGPR ring depth 8 (32 units) + softmax ======
        f32x4 accB[2][4];
        #pragma unroll
        for (int hf = 0; hf < 2; ++hf)
            #pragma unroll
            for (int jj = 0; jj < 4; ++jj) accB[hf][jj] = fz;

        i64x2 rB[8][2];
#define LDB(U, S) { const char* _p = wobase + (size_t)(U) * 16384; \
        rB[S][0] = *(const i64x2*)_p; rB[S][1] = *(const i64x2*)(_p + 1024); }
        LDB(0, 0); LDB(1, 1); LDB(2, 2); LDB(3, 3);
        LDB(4, 4); LDB(5, 5); LDB(6, 6); LDB(7, 7);

        // gumbel prefetch (compiler tracks waits per-register; no cross-counting)
        const float* gt = gum + (size_t)t * (B_ * V_) + (size_t)r0 * V_;
        f32x4 gr[2][4];
        #pragma unroll
        for (int hf = 0; hf < 2; ++hf)
            #pragma unroll
            for (int jj = 0; jj < 4; ++jj) {
                int v = (w << 7) + (hf << 6) + (jj << 4) + col;
                #pragma unroll
                for (int r = 0; r < 4; ++r)
                    gr[hf][jj][r] = __builtin_nontemporal_load(&gt[((q << 2) + r) * V_ + v]);
            }

        #pragma unroll
        for (int ks = 0; ks < 16; ++ks) {
            i64 a8 = *(const i64*)(smem + AEO + colB776 + 256u + ((u32)ks << 5) + q8);
            #pragma unroll
            for (int hf = 0; hf < 2; ++hf) {
                const int u = ks * 2 + hf, s = u & 7;
                accB[hf][0] = __builtin_amdgcn_mfma_f32_16x16x32_fp8_fp8(a8, rB[s][0][0], accB[hf][0], 0, 0, 0);
                accB[hf][1] = __builtin_amdgcn_mfma_f32_16x16x32_fp8_fp8(a8, rB[s][0][1], accB[hf][1], 0, 0, 0);
                accB[hf][2] = __builtin_amdgcn_mfma_f32_16x16x32_fp8_fp8(a8, rB[s][1][0], accB[hf][2], 0, 0, 0);
                accB[hf][3] = __builtin_amdgcn_mfma_f32_16x16x32_fp8_fp8(a8, rB[s][1][1], accB[hf][3], 0, 0, 0);
                if (u + 8 < 32) LDB(u + 8, s);
            }
        }
#undef LDB

        // z = acc*S1 + bias + gumbel (in place); row-max
        float mx[4];
        #pragma unroll
        for (int r = 0; r < 4; ++r) mx[r] = -1e30f;
        #pragma unroll
        for (int hf = 0; hf < 2; ++hf)
            #pragma unroll
            for (int jj = 0; jj < 4; ++jj)
                #pragma unroll
                for (int r = 0; r < 4; ++r) {
                    float zz = accB[hf][jj][r] * S1 + bov[hf][jj] + gr[hf][jj][r];
                    accB[hf][jj][r] = zz;
                    mx[r] = fmaxf(mx[r], zz);
                }
        #pragma unroll
        for (int m = 1; m < 16; m <<= 1)
            #pragma unroll
            for (int r = 0; r < 4; ++r) mx[r] = fmaxf(mx[r], __shfl_xor(mx[r], m, 64));
        if (col == 0) {
            #pragma unroll
            for (int r = 0; r < 4; ++r)
                *(float*)(smem + RMX + ((((q << 2) + r) << 3) + w) * 4u) = mx[r];
        }
        __syncthreads();
        float m_[4];
        #pragma unroll
        for (int r = 0; r < 4; ++r) {
            float mm = -1e30f;
            #pragma unroll
            for (int ww = 0; ww < 8; ++ww)
                mm = fmaxf(mm, *(const float*)(smem + RMX + ((((q << 2) + r) << 3) + ww) * 4u));
            m_[r] = mm;
        }
        // eb = exp(z - m) in place; row-sum; stage xs = eb*256 fp8
        float ps[4] = {0.f, 0.f, 0.f, 0.f};
        #pragma unroll
        for (int hf = 0; hf < 2; ++hf)
            #pragma unroll
            for (int jj = 0; jj < 4; ++jj) {
                u32 v = (w << 7) + (hf << 6) + (jj << 4) + col;
                #pragma unroll
                for (int r = 0; r < 4; ++r) {
                    float Ee = __expf(accB[hf][jj][r] - m_[r]);
                    accB[hf][jj][r] = Ee;
                    ps[r] += Ee;
                    *(u8*)(smem + XSO + ((q << 2) + r) * 1040u + v) = f2fp8(Ee * 256.f);
                }
            }
        #pragma unroll
        for (int m = 1; m < 16; m <<= 1)
            #pragma unroll
            for (int r = 0; r < 4; ++r) ps[r] += __shfl_xor(ps[r], m, 64);
        if (col == 0) {
            #pragma unroll
            for (int r = 0; r < 4; ++r)
                *(float*)(smem + RSM + ((((q << 2) + r) << 3) + w) * 4u) = ps[r];
        }
        __syncthreads();
        float invs[4];
        #pragma unroll
        for (int r = 0; r < 4; ++r) {
            float s = 0.f;
            #pragma unroll
            for (int ww = 0; ww < 8; ++ww)
                s += *(const float*)(smem + RSM + ((((q << 2) + r) << 3) + ww) * 4u);
            invs[r] = 1.f / s;
        }

        // ====== phase C prologue loads BEFORE out-stores ======
        f32x4 accC[2];
        accC[0] = fz; accC[1] = fz;
        i64x2 rC[4][2];
#define LDC(U, S) { const char* _p = webase + (size_t)(U) * 16384; \
        rC[S][0] = *(const i64x2*)_p; rC[S][1] = *(const i64x2*)(_p + 1024); }
        LDC(0, 0); LDC(1, 1); LDC(2, 2); LDC(3, 3);

        // normalized softmax out (fp32, nontemporal stream)
        #pragma unroll
        for (int hf = 0; hf < 2; ++hf)
            #pragma unroll
            for (int jj = 0; jj < 4; ++jj) {
                int v = (w << 7) + (hf << 6) + (jj << 4) + col;
                #pragma unroll
                for (int r = 0; r < 4; ++r) {
                    int b = (q << 2) + r;
                    __builtin_nontemporal_store(accB[hf][jj][r] * invs[r],
                        &out[((size_t)(r0 + b) * 33 + t) * V_ + v]);
                }
            }

        // ====== phase C: e_new, VGPR ring depth 4 (16 units) ======
        #pragma unroll
        for (int ksp = 0; ksp < 16; ++ksp) {
            const int s = ksp & 3;
            i64 x0 = *(const i64*)(smem + XSO + colB1040 + ((u32)ksp << 6) + q8);
            i64 x1 = *(const i64*)(smem + XSO + colB1040 + ((u32)ksp << 6) + 32u + q8);
            accC[0] = __builtin_amdgcn_mfma_f32_16x16x32_fp8_fp8(x0, rC[s][0][0], accC[0], 0, 0, 0);
            accC[1] = __builtin_amdgcn_mfma_f32_16x16x32_fp8_fp8(x0, rC[s][0][1], accC[1], 0, 0, 0);
            accC[0] = __builtin_amdgcn_mfma_f32_16x16x32_fp8_fp8(x1, rC[s][1][0], accC[0], 0, 0, 0);
            accC[1] = __builtin_amdgcn_mfma_f32_16x16x32_fp8_fp8(x1, rC[s][1][1], accC[1], 0, 0, 0);
            if (ksp + 4 < 16) LDC(ksp + 4, s);
        }
#undef LDC

        {   // e = accC*invs/(256*64) + b_emb ; store e*16 as fp8
            #pragma unroll
            for (int jj = 0; jj < 2; ++jj) {
                u32 ce = (w << 5) + (jj << 4) + col;
                #pragma unroll
                for (int r = 0; r < 4; ++r) {
                    float e_ = accC[jj][r] * invs[r] * (16.f / 16384.f) + bem16[jj];
                    *(u8*)(smem + AEO + ((q << 2) + r) * 776u + ce) = f2fp8(e_);
                }
            }
        }
        __syncthreads();            // e complete before next step's phase A
    }
}

extern "C" void kernel_launch(void* const* d_in, const int* in_sizes, int n_in,
                              void* d_out, int out_size, void* d_ws, size_t ws_size,
                              hipStream_t stream) {
    const float* x     = (const float*)d_in[0];
    const float* gum   = (const float*)d_in[1];
    const float* W_ih  = (const float*)d_in[2];
    const float* W_hh  = (const float*)d_in[3];
    const float* b_ih  = (const float*)d_in[4];
    const float* b_hh  = (const float*)d_in[5];
    const float* W_out = (const float*)d_in[6];
    const float* b_out = (const float*)d_in[7];
    const float* W_emb = (const float*)d_in[8];
    const float* b_emb = (const float*)d_in[9];
    const float* sos   = (const float*)d_in[10];
    float* out = (float*)d_out;

    char* ws = (char*)d_ws;
    u8*    w1f = (u8*)(ws);                    // 1,572,864 B (fp8)
    u8*    wof = (u8*)(ws + 1572864);          //   524,288 B (fp8)
    u8*    wef = (u8*)(ws + 2097152);          //   262,144 B (fp8)
    float* b1  = (float*)(ws + 2359296);       //     8,192 B

    prep<<<9224, 256, 0, stream>>>(W_ih, W_hh, b_ih, b_hh, W_out, W_emb,
                                   w1f, wof, wef, b1);
    lstm_fused<<<128, 512, 0, stream>>>(x, gum, w1f, wof, wef, b1,
                                        b_out, b_emb, sos, out);
}

// Round 9
// 1451.163 us; speedup vs baseline: 3.1000x; 2.9871x over previous
//
#include <hip/hip_runtime.h>
#include <hip/hip_bf16.h>

#define B_   2048
#define V_   1024
#define H_   512
#define E_   256
#define L_   32

typedef __attribute__((ext_vector_type(4))) float f32x4;
typedef unsigned short u16;
typedef unsigned int   u32;
typedef unsigned char  u8;
typedef long long      i64;

// OCP e4m3fn encode, RNE, flush below 2^-6 (callers pre-scale so this is negligible)
__device__ __forceinline__ u8 f2e4m3(float x) {
    union { float f; u32 u; } v; v.f = x;
    u32 s = (v.u >> 24) & 0x80u;
    u32 a = v.u & 0x7fffffffu;
    if (a < 0x3c800000u) return (u8)s;            // |x| < 2^-6 -> 0
    if (a > 0x43e00000u) a = 0x43e00000u;         // clamp 448
    u32 r = a + 0x000fffffu + ((a >> 20) & 1u);   // RNE to 3-bit mantissa
    if (r > 0x43e00000u) r = 0x43e00000u;
    u32 ex = (r >> 23) - 120u;
    u32 mn = (r >> 20) & 7u;
    return (u8)(s | (ex << 3) | mn);
}
__device__ __forceinline__ u8 f2fp8(float x) {
#if __has_builtin(__builtin_amdgcn_cvt_pk_fp8_f32)
    return (u8)(__builtin_amdgcn_cvt_pk_fp8_f32(x, x, 0, false) & 0xff);
#else
    return f2e4m3(x);
#endif
}
__device__ __forceinline__ float sig_(float x)  { return 1.f / (1.f + __expf(-x)); }
__device__ __forceinline__ float tanh_(float x) { return 1.f - 2.f / (__expf(2.f * x) + 1.f); }

// -------------------------------------------------------------------------
// Weight layouts, all fp8 e4m3 scaled x64, chunked for a 16-wave LDS ring.
// Chunk = 32 KB = 16 waves x 2 KB; a wave's 2 KB = 4 frags x 512 B.
// w1f: chunk c = (ks, gh):  [ks 24][gh 2][wv 16][g2 2][jj 2][l 64][e 8]
//      k = ks*32+(l>>4)*8+e,  n = (2gh+g2)*512 + wv*32 + jj*16 + (l&15)
// wof: chunk = ks:          [ks 16][wv 16][jj 4][l 64][e 8]
//      k = ks*32+(l>>4)*8+e,  v = wv*64 + jj*16 + (l&15)
// wef: chunk = ksp (4 ks):  [ksp 8][wv 16][s 4][l 64][e 8]
//      k = (4ksp+s)*32+(l>>4)*8+e,  col = wv*16 + (l&15)
// b1 = b_ih + b_hh (fp32)
// -------------------------------------------------------------------------
__global__ void prep(const float* __restrict__ W_ih, const float* __restrict__ W_hh,
                     const float* __restrict__ b_ih, const float* __restrict__ b_hh,
                     const float* __restrict__ W_out, const float* __restrict__ W_emb,
                     u8* __restrict__ w1f, u8* __restrict__ wof, u8* __restrict__ wef,
                     float* __restrict__ b1)
{
    int idx = blockIdx.x * 256 + threadIdx.x;
    if (idx < 1572864) {                       // W1 = [W_ih | W_hh] -> fp8*64
        int e = idx & 7, l = (idx >> 3) & 63, jj = (idx >> 9) & 1, g2 = (idx >> 10) & 1,
            wv = (idx >> 11) & 15, gh = (idx >> 15) & 1, ks = idx >> 16;
        int k = ks * 32 + ((l >> 4) << 3) + e;
        int n = (2 * gh + g2) * 512 + wv * 32 + jj * 16 + (l & 15);
        float v = (k < E_) ? W_ih[n * E_ + k] : W_hh[n * H_ + (k - E_)];
        w1f[idx] = f2e4m3(v * 64.f);
    } else if (idx < 2097152) {                // W_out -> fp8*64
        int j = idx - 1572864;
        int e = j & 7, l = (j >> 3) & 63, jj = (j >> 9) & 3, wv = (j >> 11) & 15, ks = j >> 15;
        int k = ks * 32 + ((l >> 4) << 3) + e;
        int v = wv * 64 + jj * 16 + (l & 15);
        wof[j] = f2e4m3(W_out[v * H_ + k] * 64.f);
    } else if (idx < 2359296) {                // W_emb -> fp8*64
        int j = idx - 2097152;
        int e = j & 7, l = (j >> 3) & 63, s = (j >> 9) & 3, wv = (j >> 11) & 15, ksp = j >> 15;
        int k = (4 * ksp + s) * 32 + ((l >> 4) << 3) + e;
        int ce = wv * 16 + (l & 15);
        wef[j] = f2e4m3(W_emb[ce * V_ + k] * 64.f);
    } else if (idx < 2361344) {
        int j = idx - 2359296;
        b1[j] = b_ih[j] + b_hh[j];
    }
}

// LDS layout (bytes)
#define STG   0u        // ring: 4 slots x 32768 (16 waves x 2 KB each)
#define AEO   131072u   // 16 x 776 fp8: [0,256) e*16, [256,768) h*16
#define XSO   143488u   // 16 x 1040 fp8 xs = exp(z-m)*256
#define RMX   160128u   // 16x16 f32 row-max partials (1 KB)
#define RSM   161152u   // 16x16 f32 row-sum partials (1 KB)
#define LDS_TOTAL 162176

#define WAITVM_(N) asm volatile("s_waitcnt vmcnt(" #N ")" ::: "memory")
#define WAITVM(N) WAITVM_(N)

typedef const __attribute__((address_space(1))) void* gvp;
typedef __attribute__((address_space(3))) void* svp;

// 1024 threads = 16 waves = 4 waves/EU; (4,4) is the PROVEN knob on this
// toolchain (r5: honored -> 128 VGPRs). All per-wave state sized for 128.
__global__ __launch_bounds__(1024)
__attribute__((amdgpu_waves_per_eu(4, 4)))
void lstm_fused(const float* __restrict__ x, const float* __restrict__ gum,
                const u8* __restrict__ w1f, const u8* __restrict__ wof,
                const u8* __restrict__ wef, const float* __restrict__ b1,
                const float* __restrict__ b_out, const float* __restrict__ b_emb,
                const float* __restrict__ sos, float* __restrict__ out)
{
    extern __shared__ char smem[];

    const u32 tid = threadIdx.x;
    const u32 w   = tid >> 6;        // wave 0..15
    const u32 l   = tid & 63u;
    const u32 q   = l >> 4;
    const u32 col = l & 15u;
    const int r0  = blockIdx.x << 4;

    const u32 wB  = w << 11;         // wave's 2 KB slice inside a chunk
    const u32 lB  = l << 4;          // l*16 (global-load lane offset)
    const u32 l8  = l << 3;          // l*8  (ds-read lane offset)
    const u32 q8  = q << 3;
    const u32 colB776  = col * 776u;
    const u32 colB1040 = col * 1040u;

    const char* w1p = (const char*)w1f;
    const char* wop = (const char*)wof;
    const char* wep = (const char*)wef;

// issue one 2 KB wave-slice of chunk C (2 x 1 KB linear global_load_lds)
#define ISS(BASE, C) do { u32 _c = (u32)(C); \
    u32 _o = (u32)__builtin_amdgcn_readfirstlane((int)(((_c & 3u) << 15) + wB)); \
    const char* _s = (BASE) + ((size_t)_c << 15) + wB + lB; \
    __builtin_amdgcn_global_load_lds((gvp)_s,          (svp)(smem + _o),          16, 0, 0); \
    __builtin_amdgcn_global_load_lds((gvp)(_s + 1024), (svp)(smem + _o + 1024u),  16, 0, 0); } while (0)

// phase A consume: chunk (ks,gh) -> gates 2gh,2gh+1, jj 0..1 (4 MFMAs)
#define CONSA(GH, C) { const char* _fb = smem + (((u32)(C) & 3u) << 15) + wB + l8; \
    acc[2*(GH)  ][0] = __builtin_amdgcn_mfma_f32_16x16x32_fp8_fp8(a8, *(const i64*)(_fb        ), acc[2*(GH)  ][0], 0, 0, 0); \
    acc[2*(GH)  ][1] = __builtin_amdgcn_mfma_f32_16x16x32_fp8_fp8(a8, *(const i64*)(_fb +  512u), acc[2*(GH)  ][1], 0, 0, 0); \
    acc[2*(GH)+1][0] = __builtin_amdgcn_mfma_f32_16x16x32_fp8_fp8(a8, *(const i64*)(_fb + 1024u), acc[2*(GH)+1][0], 0, 0, 0); \
    acc[2*(GH)+1][1] = __builtin_amdgcn_mfma_f32_16x16x32_fp8_fp8(a8, *(const i64*)(_fb + 1536u), acc[2*(GH)+1][1], 0, 0, 0); }

// phase B consume: chunk ks -> jj 0..3 (4 MFMAs)
#define CONSB(C) { const char* _fb = smem + (((u32)(C) & 3u) << 15) + wB + l8; \
    accB[0] = __builtin_amdgcn_mfma_f32_16x16x32_fp8_fp8(a8, *(const i64*)(_fb        ), accB[0], 0, 0, 0); \
    accB[1] = __builtin_amdgcn_mfma_f32_16x16x32_fp8_fp8(a8, *(const i64*)(_fb +  512u), accB[1], 0, 0, 0); \
    accB[2] = __builtin_amdgcn_mfma_f32_16x16x32_fp8_fp8(a8, *(const i64*)(_fb + 1024u), accB[2], 0, 0, 0); \
    accB[3] = __builtin_amdgcn_mfma_f32_16x16x32_fp8_fp8(a8, *(const i64*)(_fb + 1536u), accB[3], 0, 0, 0); }

// phase C consume: chunk ksp -> s 0..3 (4 MFMAs, per-s xs operand)
#define CONSC(C) { const char* _fb = smem + (((u32)(C) & 3u) << 15) + wB + l8; \
    u32 _kb = ((u32)(C)) << 7; \
    accC = __builtin_amdgcn_mfma_f32_16x16x32_fp8_fp8(*(const i64*)(smem + XSO + colB1040 + _kb       + q8), *(const i64*)(_fb        ), accC, 0, 0, 0); \
    accC = __builtin_amdgcn_mfma_f32_16x16x32_fp8_fp8(*(const i64*)(smem + XSO + colB1040 + _kb + 32u + q8), *(const i64*)(_fb +  512u), accC, 0, 0, 0); \
    accC = __builtin_amdgcn_mfma_f32_16x16x32_fp8_fp8(*(const i64*)(smem + XSO + colB1040 + _kb + 64u + q8), *(const i64*)(_fb + 1024u), accC, 0, 0, 0); \
    accC = __builtin_amdgcn_mfma_f32_16x16x32_fp8_fp8(*(const i64*)(smem + XSO + colB1040 + _kb + 96u + q8), *(const i64*)(_fb + 1536u), accC, 0, 0, 0); }

    // EOS row (nontemporal; drained once by first phase-A wait)
    for (u32 i = tid; i < 16 * V_; i += 1024) {
        u32 b = i >> 10, v = i & (V_ - 1);
        __builtin_nontemporal_store((v == 0) ? 1.f : 0.f,
                                    &out[((size_t)(r0 + b) * 33 + 32) * V_ + v]);
    }
    // e0 = sos*16 (fp8), h0 = x*16 (fp8)
    for (u32 i = tid; i < 16 * E_; i += 1024) {
        u32 b = i >> 8, k = i & (E_ - 1);
        *(u8*)(smem + AEO + b * 776u + k) = f2fp8(sos[k] * 16.f);
    }
    for (u32 i = tid; i < 16 * H_; i += 1024) {
        u32 b = i >> 9, k = i & (H_ - 1);
        *(u8*)(smem + AEO + b * 776u + 256u + k) = f2fp8(x[(r0 + b) * H_ + k] * 16.f);
    }

    // hoisted biases: wave owns j in [32w, 32w+32) per gate
    float bia[2], bfa[2], bga[2], boa[2];
    #pragma unroll
    for (int jj = 0; jj < 2; ++jj) {
        int j = (w << 5) + (jj << 4) + col;
        bia[jj] = b1[j];           bfa[jj] = b1[H_ + j];
        bga[jj] = b1[2 * H_ + j];  boa[jj] = b1[3 * H_ + j];
    }
    float bov[4];
    #pragma unroll
    for (int jj = 0; jj < 4; ++jj)
        bov[jj] = b_out[(w << 6) + (jj << 4) + col];
    const float bem16 = b_emb[(w << 4) + col] * 16.f;

    float creg[2][4];
    #pragma unroll
    for (int jj = 0; jj < 2; ++jj)
        #pragma unroll
        for (int r = 0; r < 4; ++r) creg[jj][r] = 0.f;

    __syncthreads();

    const f32x4 fz = {0.f, 0.f, 0.f, 0.f};
    const float S1 = 1.f / 1024.f;            // 1/(A_SC*W_SC) = 1/(16*64)

    #pragma unroll 1
    for (int t = 0; t < L_; ++t) {
        // ====== phase A: gates, ring-4 of 32 KB chunks (48 chunks) ======
        f32x4 acc[4][2];
        #pragma unroll
        for (int g = 0; g < 4; ++g) { acc[g][0] = fz; acc[g][1] = fz; }

        ISS(w1p, 0); ISS(w1p, 1); ISS(w1p, 2);
        #pragma unroll 1
        for (int ks = 0; ks < 22; ++ks) {
            i64 a8 = *(const i64*)(smem + AEO + colB776 + ((u32)ks << 5) + q8);
            const int c0 = ks << 1;
            WAITVM(4); CONSA(0, c0);     ISS(w1p, c0 + 3);
            WAITVM(4); CONSA(1, c0 + 1); ISS(w1p, c0 + 4);
        }
        {   // ks=22: chunks 44,45 (issue last chunk 47)
            i64 a8 = *(const i64*)(smem + AEO + colB776 + (22u << 5) + q8);
            WAITVM(4); CONSA(0, 44); ISS(w1p, 47);
            WAITVM(4); CONSA(1, 45);
        }
        {   // ks=23: chunks 46,47
            i64 a8 = *(const i64*)(smem + AEO + colB776 + (23u << 5) + q8);
            WAITVM(2); CONSA(0, 46);
            WAITVM(0); CONSA(1, 47);
        }

        // gumbel prefetch NOW (overlaps pointwise + sync + B prologue; the
        // one-time drain it causes in B's first wait is ~HBM latency)
        const float* gt = gum + (size_t)t * (B_ * V_) + (size_t)r0 * V_;
        f32x4 gr[4];
        #pragma unroll
        for (int jj = 0; jj < 4; ++jj) {
            int v = (w << 6) + (jj << 4) + col;
            #pragma unroll
            for (int r = 0; r < 4; ++r)
                gr[jj][r] = __builtin_nontemporal_load(&gt[((q << 2) + r) * V_ + v]);
        }

        __syncthreads();            // all AEO reads done before h overwrite
        #pragma unroll
        for (int jj = 0; jj < 2; ++jj) {
            int j = (w << 5) + (jj << 4) + col;
            #pragma unroll
            for (int r = 0; r < 4; ++r) {
                float gi = sig_(acc[0][jj][r] * S1 + bia[jj]);
                float gf = sig_(acc[1][jj][r] * S1 + bfa[jj]);
                float gg = tanh_(acc[2][jj][r] * S1 + bga[jj]);
                float go = sig_(acc[3][jj][r] * S1 + boa[jj]);
                float c  = gf * creg[jj][r] + gi * gg;
                creg[jj][r] = c;
                float h = go * tanh_(c);
                *(u8*)(smem + AEO + ((q << 2) + r) * 776u + 256u + (u32)j) = f2fp8(h * 16.f);
            }
        }
        __syncthreads();            // h complete

        // ====== phase B: logits, ring-4 (16 chunks) + softmax ======
        f32x4 accB[4];
        #pragma unroll
        for (int jj = 0; jj < 4; ++jj) accB[jj] = fz;

        ISS(wop, 0); ISS(wop, 1); ISS(wop, 2);
        #pragma unroll 1
        for (int ks = 0; ks < 13; ++ks) {
            i64 a8 = *(const i64*)(smem + AEO + colB776 + 256u + ((u32)ks << 5) + q8);
            WAITVM(4); CONSB(ks); ISS(wop, ks + 3);
        }
        {   i64 a8 = *(const i64*)(smem + AEO + colB776 + 256u + (13u << 5) + q8);
            WAITVM(4); CONSB(13); }
        {   i64 a8 = *(const i64*)(smem + AEO + colB776 + 256u + (14u << 5) + q8);
            WAITVM(2); CONSB(14); }
        {   i64 a8 = *(const i64*)(smem + AEO + colB776 + 256u + (15u << 5) + q8);
            WAITVM(0); CONSB(15); }

        // z = acc*S1 + bias + gumbel (in place); row-max
        float mx[4];
        #pragma unroll
        for (int r = 0; r < 4; ++r) mx[r] = -1e30f;
        #pragma unroll
        for (int jj = 0; jj < 4; ++jj)
            #pragma unroll
            for (int r = 0; r < 4; ++r) {
                float zz = accB[jj][r] * S1 + bov[jj] + gr[jj][r];
                accB[jj][r] = zz;
                mx[r] = fmaxf(mx[r], zz);
            }
        #pragma unroll
        for (int m = 1; m < 16; m <<= 1)
            #pragma unroll
            for (int r = 0; r < 4; ++r) mx[r] = fmaxf(mx[r], __shfl_xor(mx[r], m, 64));
        if (col == 0) {
            #pragma unroll
            for (int r = 0; r < 4; ++r)
                *(float*)(smem + RMX + ((((q << 2) + r) << 4) + w) * 4u) = mx[r];
        }
        __syncthreads();
        float m_[4];
        #pragma unroll
        for (int r = 0; r < 4; ++r) {
            float mm = -1e30f;
            #pragma unroll
            for (int ww = 0; ww < 16; ++ww)
                mm = fmaxf(mm, *(const float*)(smem + RMX + ((((q << 2) + r) << 4) + ww) * 4u));
            m_[r] = mm;
        }
        // eb = exp(z-m) in place; row-sum; stage xs = eb*256 fp8
        float ps[4] = {0.f, 0.f, 0.f, 0.f};
        #pragma unroll
        for (int jj = 0; jj < 4; ++jj) {
            u32 v = (w << 6) + (jj << 4) + col;
            #pragma unroll
            for (int r = 0; r < 4; ++r) {
                float Ee = __expf(accB[jj][r] - m_[r]);
                accB[jj][r] = Ee;
                ps[r] += Ee;
                *(u8*)(smem + XSO + ((q << 2) + r) * 1040u + v) = f2fp8(Ee * 256.f);
            }
        }
        #pragma unroll
        for (int m = 1; m < 16; m <<= 1)
            #pragma unroll
            for (int r = 0; r < 4; ++r) ps[r] += __shfl_xor(ps[r], m, 64);
        if (col == 0) {
            #pragma unroll
            for (int r = 0; r < 4; ++r)
                *(float*)(smem + RSM + ((((q << 2) + r) << 4) + w) * 4u) = ps[r];
        }
        __syncthreads();            // xs + RSM visible
        float invs[4];
        #pragma unroll
        for (int r = 0; r < 4; ++r) {
            float s = 0.f;
            #pragma unroll
            for (int ww = 0; ww < 16; ++ww)
                s += *(const float*)(smem + RSM + ((((q << 2) + r) << 4) + ww) * 4u);
            invs[r] = 1.f / s;
        }

        // ====== phase C: e_new, ring-4 (8 chunks); stores AFTER ring ======
        f32x4 accC = fz;
        ISS(wep, 0); ISS(wep, 1); ISS(wep, 2);
        #pragma unroll 1
        for (int c2 = 0; c2 < 5; ++c2) {
            WAITVM(4); CONSC(c2); ISS(wep, c2 + 3);
        }
        WAITVM(4); CONSC(5);
        WAITVM(2); CONSC(6);
        WAITVM(0); CONSC(7);

        // normalized softmax out (after ring: stores never pollute WAITVM)
        #pragma unroll
        for (int jj = 0; jj < 4; ++jj) {
            int v = (w << 6) + (jj << 4) + col;
            #pragma unroll
            for (int r = 0; r < 4; ++r) {
                int b = (q << 2) + r;
                __builtin_nontemporal_store(accB[jj][r] * invs[r],
                    &out[((size_t)(r0 + b) * 33 + t) * V_ + v]);
            }
        }

        {   // e = accC*invs/(256*64) + b_emb ; store e*16 as fp8
            u32 ce = (w << 4) + col;
            #pragma unroll
            for (int r = 0; r < 4; ++r) {
                float e_ = accC[r] * invs[r] * (16.f / 16384.f) + bem16;
                *(u8*)(smem + AEO + ((q << 2) + r) * 776u + ce) = f2fp8(e_);
            }
        }
        __syncthreads();            // e complete before next step's phase A
    }
#undef ISS
#undef CONSA
#undef CONSB
#undef CONSC
}

extern "C" void kernel_launch(void* const* d_in, const int* in_sizes, int n_in,
                              void* d_out, int out_size, void* d_ws, size_t ws_size,
                              hipStream_t stream) {
    const float* x     = (const float*)d_in[0];
    const float* gum   = (const float*)d_in[1];
    const float* W_ih  = (const float*)d_in[2];
    const float* W_hh  = (const float*)d_in[3];
    const float* b_ih  = (const float*)d_in[4];
    const float* b_hh  = (const float*)d_in[5];
    const float* W_out = (const float*)d_in[6];
    const float* b_out = (const float*)d_in[7];
    const float* W_emb = (const float*)d_in[8];
    const float* b_emb = (const float*)d_in[9];
    const float* sos   = (const float*)d_in[10];
    float* out = (float*)d_out;

    char* ws = (char*)d_ws;
    u8*    w1f = (u8*)(ws);                    // 1,572,864 B (fp8)
    u8*    wof = (u8*)(ws + 1572864);          //   524,288 B (fp8)
    u8*    wef = (u8*)(ws + 2097152);          //   262,144 B (fp8)
    float* b1  = (float*)(ws + 2359296);       //     8,192 B

    hipFuncSetAttribute((const void*)lstm_fused,
                        hipFuncAttributeMaxDynamicSharedMemorySize, LDS_TOTAL);

    prep<<<9224, 256, 0, stream>>>(W_ih, W_hh, b_ih, b_hh, W_out, W_emb,
                                   w1f, wof, wef, b1);
    lstm_fused<<<128, 1024, LDS_TOTAL, stream>>>(x, gum, w1f, wof, wef, b1,
                                                 b_out, b_emb, sos, out);
}

// Round 10
// 1209.175 us; speedup vs baseline: 3.7204x; 1.2001x over previous
//
#include <hip/hip_runtime.h>
#include <hip/hip_bf16.h>

#define B_   2048
#define V_   1024
#define H_   512
#define E_   256
#define L_   32

typedef __attribute__((ext_vector_type(4))) float f32x4;
typedef unsigned short u16;
typedef unsigned int   u32;
typedef unsigned char  u8;
typedef long long      i64;

// OCP e4m3fn encode, RNE, flush below 2^-6 (callers pre-scale so this is negligible)
__device__ __forceinline__ u8 f2e4m3(float x) {
    union { float f; u32 u; } v; v.f = x;
    u32 s = (v.u >> 24) & 0x80u;
    u32 a = v.u & 0x7fffffffu;
    if (a < 0x3c800000u) return (u8)s;            // |x| < 2^-6 -> 0
    if (a > 0x43e00000u) a = 0x43e00000u;         // clamp 448
    u32 r = a + 0x000fffffu + ((a >> 20) & 1u);   // RNE to 3-bit mantissa
    if (r > 0x43e00000u) r = 0x43e00000u;
    u32 ex = (r >> 23) - 120u;
    u32 mn = (r >> 20) & 7u;
    return (u8)(s | (ex << 3) | mn);
}
__device__ __forceinline__ u8 f2fp8(float x) {
#if __has_builtin(__builtin_amdgcn_cvt_pk_fp8_f32)
    return (u8)(__builtin_amdgcn_cvt_pk_fp8_f32(x, x, 0, false) & 0xff);
#else
    return f2e4m3(x);
#endif
}
__device__ __forceinline__ float sig_(float x)  { return 1.f / (1.f + __expf(-x)); }
__device__ __forceinline__ float tanh_(float x) { return 1.f - 2.f / (__expf(2.f * x) + 1.f); }

// -------------------------------------------------------------------------
// Weight layouts (identical to the 1220us r6 kernel), all fp8 e4m3 x64.
// Chunk = 16 KB = 8 waves x 2 KB; a wave's 2 KB = 4 frags x 512 B.
// w1f: chunk c = (ks, g):   [ks 24][g 4][wv 8][jj 4][l 64][e 8]
//      k = ks*32+(l>>4)*8+e,  n = g*512 + wv*64 + jj*16 + (l&15)
// wof: chunk c = (ks, hf):  [ks 16][hf 2][wv 8][jj 4][l 64][e 8]
//      k = ks*32+(l>>4)*8+e,  v = wv*128 + hf*64 + jj*16 + (l&15)
// wef: chunk = ksp:         [ksp 16][wv 8][s 2][jj 2][l 64][e 8]
//      k = (2*ksp+s)*32+(l>>4)*8+e,  col = wv*32 + jj*16 + (l&15)
// b1 = b_ih + b_hh (fp32)
// -------------------------------------------------------------------------
__global__ void prep(const float* __restrict__ W_ih, const float* __restrict__ W_hh,
                     const float* __restrict__ b_ih, const float* __restrict__ b_hh,
                     const float* __restrict__ W_out, const float* __restrict__ W_emb,
                     u8* __restrict__ w1f, u8* __restrict__ wof, u8* __restrict__ wef,
                     float* __restrict__ b1)
{
    int idx = blockIdx.x * 256 + threadIdx.x;
    if (idx < 1572864) {                       // W1 = [W_ih | W_hh] -> fp8*64
        int e = idx & 7, l = (idx >> 3) & 63, jj = (idx >> 9) & 3, wv = (idx >> 11) & 7,
            g = (idx >> 14) & 3, ks = idx >> 16;
        int k = ks * 32 + ((l >> 4) << 3) + e;
        int n = g * 512 + wv * 64 + jj * 16 + (l & 15);
        float v = (k < E_) ? W_ih[n * E_ + k] : W_hh[n * H_ + (k - E_)];
        w1f[idx] = f2e4m3(v * 64.f);
    } else if (idx < 2097152) {                // W_out -> fp8*64
        int j = idx - 1572864;
        int e = j & 7, l = (j >> 3) & 63, jj = (j >> 9) & 3, wv = (j >> 11) & 7,
            hf = (j >> 14) & 1, ks = j >> 15;
        int k = ks * 32 + ((l >> 4) << 3) + e;
        int v = wv * 128 + hf * 64 + jj * 16 + (l & 15);
        wof[j] = f2e4m3(W_out[v * H_ + k] * 64.f);
    } else if (idx < 2359296) {                // W_emb -> fp8*64
        int j = idx - 2097152;
        int e = j & 7, l = (j >> 3) & 63, jj = (j >> 9) & 1, s = (j >> 10) & 1,
            wv = (j >> 11) & 7, ksp = j >> 14;
        int k = (2 * ksp + s) * 32 + ((l >> 4) << 3) + e;
        int ce = wv * 32 + jj * 16 + (l & 15);
        wef[j] = f2e4m3(W_emb[ce * V_ + k] * 64.f);
    } else if (idx < 2361344) {
        int j = idx - 2359296;
        b1[j] = b_ih[j] + b_hh[j];
    }
}

// LDS layout (bytes)
#define STG   0u        // ring: 8 slots x 16384 (8 waves x 2 KB each)
#define AEO   131072u   // 16 x 776 fp8: [0,256) e*16, [256,768) h*16
#define XSO   143488u   // 16 x 1040 fp8 xs = exp(z-m)*256
#define RMX   160128u   // 16x8 f32 row-max partials (1 KB slot)
#define RSM   161152u   // 16x8 f32 row-sum partials (1 KB slot)
#define LDS_TOTAL 162176

#define WAITVM_(N) asm volatile("s_waitcnt vmcnt(" #N ")" ::: "memory")
#define WAITVM(N) WAITVM_(N)

typedef const __attribute__((address_space(1))) void* gvp;
typedef __attribute__((address_space(3))) void* svp;

__global__ __launch_bounds__(512, 2)
void lstm_fused(const float* __restrict__ x, const float* __restrict__ gum,
                const u8* __restrict__ w1f, const u8* __restrict__ wof,
                const u8* __restrict__ wef, const float* __restrict__ b1,
                const float* __restrict__ b_out, const float* __restrict__ b_emb,
                const float* __restrict__ sos, float* __restrict__ out)
{
    extern __shared__ char smem[];

    const u32 tid = threadIdx.x;
    const u32 w   = tid >> 6;        // wave 0..7
    const u32 l   = tid & 63u;
    const u32 q   = l >> 4;
    const u32 col = l & 15u;
    const int r0  = blockIdx.x << 4;

    // ---- L2 de-hotspot: rotate each block's chunk-consumption order so the
    // 16 CUs on an XCD read 16 DIFFERENT weight regions at any instant
    // (no L2 multicast: same-line lockstep reads serialize on one bank).
    const u32 cu    = (blockIdx.x >> 3) & 15u;   // CU-slot within XCD (round-robin map)
    const u32 ksA0  = (cu * 5u)  % 24u;          // 5 coprime 24 -> 16 distinct starts
    const u32 ksB0  = (cu * 3u)  % 16u;          // 3 coprime 16
    const u32 ksC0  = (cu * 3u)  % 16u;

    const u32 wB  = w << 11;         // wave's 2 KB slice inside a chunk
    const u32 lB  = l << 4;          // l*16 (global-load lane offset)
    const u32 l8  = l << 3;          // l*8  (ds-read lane offset)
    const u32 q8  = q << 3;
    const u32 colB776  = col * 776u;
    const u32 colB1040 = col * 1040u;

    const char* w1p = (const char*)w1f;
    const char* wop = (const char*)wof;
    const char* wep = (const char*)wef;

// issue one 2 KB wave-slice of chunk C into ring slot SLOT (2 x 1 KB loads)
#define ISS2(BASE, C, SLOT) do { \
    u32 _o = (u32)__builtin_amdgcn_readfirstlane((int)((((u32)(SLOT) & 7u) << 14) + wB)); \
    const char* _s = (BASE) + ((size_t)(u32)(C) << 14) + wB + lB; \
    __builtin_amdgcn_global_load_lds((gvp)_s,          (svp)(smem + _o),          16, 0, 0); \
    __builtin_amdgcn_global_load_lds((gvp)(_s + 1024), (svp)(smem + _o + 1024u),  16, 0, 0); } while (0)

// rotated issue helpers: I = issue index; chunk id derived from rotated ks
#define ISSA(I) do { u32 _i = (u32)(I); u32 _k = ksA0 + (_i >> 2); if (_k >= 24u) _k -= 24u; \
    ISS2(w1p, (_k << 2) | (_i & 3u), _i); } while (0)
#define ISSB(I) do { u32 _i = (u32)(I); u32 _k = ksB0 + (_i >> 1); if (_k >= 16u) _k -= 16u; \
    ISS2(wop, (_k << 1) | (_i & 1u), _i); } while (0)
#define ISSC(I) do { u32 _i = (u32)(I); u32 _k = ksC0 + _i; if (_k >= 16u) _k -= 16u; \
    ISS2(wep, _k, _i); } while (0)

// consumes keyed by issue index (ring slot = I & 7)
#define CONSA(G, I) { const char* _fb = smem + (((u32)(I) & 7u) << 14) + wB + l8; \
    acc[G][0] = __builtin_amdgcn_mfma_f32_16x16x32_fp8_fp8(a8, *(const i64*)(_fb        ), acc[G][0], 0, 0, 0); \
    acc[G][1] = __builtin_amdgcn_mfma_f32_16x16x32_fp8_fp8(a8, *(const i64*)(_fb +  512u), acc[G][1], 0, 0, 0); \
    acc[G][2] = __builtin_amdgcn_mfma_f32_16x16x32_fp8_fp8(a8, *(const i64*)(_fb + 1024u), acc[G][2], 0, 0, 0); \
    acc[G][3] = __builtin_amdgcn_mfma_f32_16x16x32_fp8_fp8(a8, *(const i64*)(_fb + 1536u), acc[G][3], 0, 0, 0); }

#define CONSB(HF, I) { const char* _fb = smem + (((u32)(I) & 7u) << 14) + wB + l8; \
    accB[HF][0] = __builtin_amdgcn_mfma_f32_16x16x32_fp8_fp8(a8, *(const i64*)(_fb        ), accB[HF][0], 0, 0, 0); \
    accB[HF][1] = __builtin_amdgcn_mfma_f32_16x16x32_fp8_fp8(a8, *(const i64*)(_fb +  512u), accB[HF][1], 0, 0, 0); \
    accB[HF][2] = __builtin_amdgcn_mfma_f32_16x16x32_fp8_fp8(a8, *(const i64*)(_fb + 1024u), accB[HF][2], 0, 0, 0); \
    accB[HF][3] = __builtin_amdgcn_mfma_f32_16x16x32_fp8_fp8(a8, *(const i64*)(_fb + 1536u), accB[HF][3], 0, 0, 0); }

#define CONSC(I) { u32 _k = ksC0 + (u32)(I); if (_k >= 16u) _k -= 16u; \
    const char* _fb = smem + (((u32)(I) & 7u) << 14) + wB + l8; \
    i64 _x0 = *(const i64*)(smem + XSO + colB1040 + ((2u * _k)      << 5) + q8); \
    i64 _x1 = *(const i64*)(smem + XSO + colB1040 + ((2u * _k + 1u) << 5) + q8); \
    accC[0] = __builtin_amdgcn_mfma_f32_16x16x32_fp8_fp8(_x0, *(const i64*)(_fb        ), accC[0], 0, 0, 0); \
    accC[1] = __builtin_amdgcn_mfma_f32_16x16x32_fp8_fp8(_x0, *(const i64*)(_fb +  512u), accC[1], 0, 0, 0); \
    accC[0] = __builtin_amdgcn_mfma_f32_16x16x32_fp8_fp8(_x1, *(const i64*)(_fb + 1024u), accC[0], 0, 0, 0); \
    accC[1] = __builtin_amdgcn_mfma_f32_16x16x32_fp8_fp8(_x1, *(const i64*)(_fb + 1536u), accC[1], 0, 0, 0); }

    // EOS row (nontemporal stream)
    for (u32 i = tid; i < 16 * V_; i += 512) {
        u32 b = i >> 10, v = i & (V_ - 1);
        __builtin_nontemporal_store((v == 0) ? 1.f : 0.f,
                                    &out[((size_t)(r0 + b) * 33 + 32) * V_ + v]);
    }
    // e0 = sos*16 (fp8), h0 = x*16 (fp8)
    for (u32 i = tid; i < 16 * E_; i += 512) {
        u32 b = i >> 8, k = i & (E_ - 1);
        *(u8*)(smem + AEO + b * 776u + k) = f2fp8(sos[k] * 16.f);
    }
    for (u32 i = tid; i < 16 * H_; i += 512) {
        u32 b = i >> 9, k = i & (H_ - 1);
        *(u8*)(smem + AEO + b * 776u + 256u + k) = f2fp8(x[(r0 + b) * H_ + k] * 16.f);
    }

    // hoisted biases: wave owns j in [64w, 64w+64)
    float bia[4], bfa[4], bga[4], boa[4];
    #pragma unroll
    for (int jj = 0; jj < 4; ++jj) {
        int j = (w << 6) + (jj << 4) + col;
        bia[jj] = b1[j];           bfa[jj] = b1[H_ + j];
        bga[jj] = b1[2 * H_ + j];  boa[jj] = b1[3 * H_ + j];
    }
    float bov[2][4];
    #pragma unroll
    for (int hf = 0; hf < 2; ++hf)
        #pragma unroll
        for (int jj = 0; jj < 4; ++jj)
            bov[hf][jj] = b_out[(w << 7) + (hf << 6) + (jj << 4) + col];
    float bem16[2];
    #pragma unroll
    for (int jj = 0; jj < 2; ++jj)
        bem16[jj] = b_emb[(w << 5) + (jj << 4) + col] * 16.f;

    float creg[4][4];
    #pragma unroll
    for (int jj = 0; jj < 4; ++jj)
        #pragma unroll
        for (int r = 0; r < 4; ++r) creg[jj][r] = 0.f;

    __syncthreads();

    const f32x4 fz = {0.f, 0.f, 0.f, 0.f};
    const float S1 = 1.f / 1024.f;            // 1/(A_SC*W_SC) = 1/(16*64)

    #pragma unroll 1
    for (int t = 0; t < L_; ++t) {
        // ====== phase A: gates, ring-8 (96 chunk-slices, rotated order) ======
        f32x4 acc[4][4];
        #pragma unroll
        for (int g = 0; g < 4; ++g)
            #pragma unroll
            for (int jj = 0; jj < 4; ++jj) acc[g][jj] = fz;

        ISSA(0); ISSA(1); ISSA(2); ISSA(3); ISSA(4); ISSA(5); ISSA(6);
        #pragma unroll 1
        for (u32 j = 0; j < 22; ++j) {
            u32 ks = ksA0 + j; if (ks >= 24u) ks -= 24u;
            i64 a8 = *(const i64*)(smem + AEO + colB776 + (ks << 5) + q8);
            u32 i0 = j << 2;
            WAITVM(12); CONSA(0, i0);     ISSA(i0 + 7);
            WAITVM(12); CONSA(1, i0 + 1); ISSA(i0 + 8);
            WAITVM(12); CONSA(2, i0 + 2); ISSA(i0 + 9);
            WAITVM(12); CONSA(3, i0 + 3); ISSA(i0 + 10);
        }
        {   // j=22: consumes 88..91, last issue 95
            u32 ks = ksA0 + 22u; if (ks >= 24u) ks -= 24u;
            i64 a8 = *(const i64*)(smem + AEO + colB776 + (ks << 5) + q8);
            WAITVM(12); CONSA(0, 88); ISSA(95);
            WAITVM(12); CONSA(1, 89);
            WAITVM(10); CONSA(2, 90);
            WAITVM(8);  CONSA(3, 91);
        }
        {   // j=23: consumes 92..95
            u32 ks = ksA0 + 23u; if (ks >= 24u) ks -= 24u;
            i64 a8 = *(const i64*)(smem + AEO + colB776 + (ks << 5) + q8);
            WAITVM(6); CONSA(0, 92);
            WAITVM(4); CONSA(1, 93);
            WAITVM(2); CONSA(2, 94);
            WAITVM(0); CONSA(3, 95);
        }
        __syncthreads();            // all AEO reads done before h overwrite

        #pragma unroll
        for (int jj = 0; jj < 4; ++jj) {
            int j = (w << 6) + (jj << 4) + col;
            #pragma unroll
            for (int r = 0; r < 4; ++r) {
                float gi = sig_(acc[0][jj][r] * S1 + bia[jj]);
                float gf = sig_(acc[1][jj][r] * S1 + bfa[jj]);
                float gg = tanh_(acc[2][jj][r] * S1 + bga[jj]);
                float go = sig_(acc[3][jj][r] * S1 + boa[jj]);
                float c  = gf * creg[jj][r] + gi * gg;
                creg[jj][r] = c;
                float h = go * tanh_(c);
                *(u8*)(smem + AEO + ((q << 2) + r) * 776u + 256u + (u32)j) = f2fp8(h * 16.f);
            }
        }
        __syncthreads();            // h complete

        // ====== phase B: logits, ring-8 (32 chunk-slices, rotated) + softmax ======
        const float* gt = gum + (size_t)t * (B_ * V_) + (size_t)r0 * V_;
        f32x4 gr[2][4];
        #pragma unroll
        for (int hf = 0; hf < 2; ++hf)
            #pragma unroll
            for (int jj = 0; jj < 4; ++jj) {
                int v = (w << 7) + (hf << 6) + (jj << 4) + col;
                #pragma unroll
                for (int r = 0; r < 4; ++r)
                    gr[hf][jj][r] = __builtin_nontemporal_load(&gt[((q << 2) + r) * V_ + v]);
            }

        f32x4 accB[2][4];
        #pragma unroll
        for (int hf = 0; hf < 2; ++hf)
            #pragma unroll
            for (int jj = 0; jj < 4; ++jj) accB[hf][jj] = fz;

        ISSB(0); ISSB(1); ISSB(2); ISSB(3); ISSB(4); ISSB(5); ISSB(6);
        #pragma unroll 1
        for (u32 j = 0; j < 12; ++j) {
            u32 ks = ksB0 + j; if (ks >= 16u) ks -= 16u;
            i64 a8 = *(const i64*)(smem + AEO + colB776 + 256u + (ks << 5) + q8);
            u32 i0 = j << 1;
            WAITVM(12); CONSB(0, i0);     ISSB(i0 + 7);
            WAITVM(12); CONSB(1, i0 + 1); ISSB(i0 + 8);
        }
        {   u32 ks = ksB0 + 12u; if (ks >= 16u) ks -= 16u;
            i64 a8 = *(const i64*)(smem + AEO + colB776 + 256u + (ks << 5) + q8);
            WAITVM(12); CONSB(0, 24); ISSB(31);
            WAITVM(12); CONSB(1, 25);
        }
        {   u32 ks = ksB0 + 13u; if (ks >= 16u) ks -= 16u;
            i64 a8 = *(const i64*)(smem + AEO + colB776 + 256u + (ks << 5) + q8);
            WAITVM(10); CONSB(0, 26);
            WAITVM(8);  CONSB(1, 27);
        }
        {   u32 ks = ksB0 + 14u; if (ks >= 16u) ks -= 16u;
            i64 a8 = *(const i64*)(smem + AEO + colB776 + 256u + (ks << 5) + q8);
            WAITVM(6); CONSB(0, 28);
            WAITVM(4); CONSB(1, 29);
        }
        {   u32 ks = ksB0 + 15u; if (ks >= 16u) ks -= 16u;
            i64 a8 = *(const i64*)(smem + AEO + colB776 + 256u + (ks << 5) + q8);
            WAITVM(2); CONSB(0, 30);
            WAITVM(0); CONSB(1, 31);
        }

        // z = acc*S1 + bias + gumbel (in place); row-max
        float mx[4];
        #pragma unroll
        for (int r = 0; r < 4; ++r) mx[r] = -1e30f;
        #pragma unroll
        for (int hf = 0; hf < 2; ++hf)
            #pragma unroll
            for (int jj = 0; jj < 4; ++jj)
                #pragma unroll
                for (int r = 0; r < 4; ++r) {
                    float zz = accB[hf][jj][r] * S1 + bov[hf][jj] + gr[hf][jj][r];
                    accB[hf][jj][r] = zz;
                    mx[r] = fmaxf(mx[r], zz);
                }
        #pragma unroll
        for (int m = 1; m < 16; m <<= 1)
            #pragma unroll
            for (int r = 0; r < 4; ++r) mx[r] = fmaxf(mx[r], __shfl_xor(mx[r], m, 64));
        if (col == 0) {
            #pragma unroll
            for (int r = 0; r < 4; ++r)
                *(float*)(smem + RMX + ((((q << 2) + r) << 3) + w) * 4u) = mx[r];
        }
        __syncthreads();
        float m_[4];
        #pragma unroll
        for (int r = 0; r < 4; ++r) {
            float mm = -1e30f;
            #pragma unroll
            for (int ww = 0; ww < 8; ++ww)
                mm = fmaxf(mm, *(const float*)(smem + RMX + ((((q << 2) + r) << 3) + ww) * 4u));
            m_[r] = mm;
        }
        // eb = exp(z-m) in place; row-sum; stage xs = eb*256 fp8
        float ps[4] = {0.f, 0.f, 0.f, 0.f};
        #pragma unroll
        for (int hf = 0; hf < 2; ++hf)
            #pragma unroll
            for (int jj = 0; jj < 4; ++jj) {
                u32 v = (w << 7) + (hf << 6) + (jj << 4) + col;
                #pragma unroll
                for (int r = 0; r < 4; ++r) {
                    float Ee = __expf(accB[hf][jj][r] - m_[r]);
                    accB[hf][jj][r] = Ee;
                    ps[r] += Ee;
                    *(u8*)(smem + XSO + ((q << 2) + r) * 1040u + v) = f2fp8(Ee * 256.f);
                }
            }
        #pragma unroll
        for (int m = 1; m < 16; m <<= 1)
            #pragma unroll
            for (int r = 0; r < 4; ++r) ps[r] += __shfl_xor(ps[r], m, 64);
        if (col == 0) {
            #pragma unroll
            for (int r = 0; r < 4; ++r)
                *(float*)(smem + RSM + ((((q << 2) + r) << 3) + w) * 4u) = ps[r];
        }
        __syncthreads();
        float invs[4];
        #pragma unroll
        for (int r = 0; r < 4; ++r) {
            float s = 0.f;
            #pragma unroll
            for (int ww = 0; ww < 8; ++ww)
                s += *(const float*)(smem + RSM + ((((q << 2) + r) << 3) + ww) * 4u);
            invs[r] = 1.f / s;
        }
        // normalized softmax out (fp32, nontemporal stream)
        #pragma unroll
        for (int hf = 0; hf < 2; ++hf)
            #pragma unroll
            for (int jj = 0; jj < 4; ++jj) {
                int v = (w << 7) + (hf << 6) + (jj << 4) + col;
                #pragma unroll
                for (int r = 0; r < 4; ++r) {
                    int b = (q << 2) + r;
                    __builtin_nontemporal_store(accB[hf][jj][r] * invs[r],
                        &out[((size_t)(r0 + b) * 33 + t) * V_ + v]);
                }
            }

        // ====== phase C: e_new, ring-8 (16 chunk-slices, rotated) ======
        f32x4 accC[2];
        accC[0] = fz; accC[1] = fz;
        ISSC(0); ISSC(1); ISSC(2); ISSC(3); ISSC(4); ISSC(5); ISSC(6);
        #pragma unroll 1
        for (u32 c2 = 0; c2 < 9; ++c2) {
            WAITVM(12); CONSC(c2); ISSC(c2 + 7);
        }
        WAITVM(12); CONSC(9);
        WAITVM(10); CONSC(10);
        WAITVM(8);  CONSC(11);
        WAITVM(6);  CONSC(12);
        WAITVM(4);  CONSC(13);
        WAITVM(2);  CONSC(14);
        WAITVM(0);  CONSC(15);

        {   // e = accC*invs/(256*64) + b_emb ; store e*16 as fp8
            #pragma unroll
            for (int jj = 0; jj < 2; ++jj) {
                u32 ce = (w << 5) + (jj << 4) + col;
                #pragma unroll
                for (int r = 0; r < 4; ++r) {
                    float e_ = accC[jj][r] * invs[r] * (16.f / 16384.f) + bem16[jj];
                    *(u8*)(smem + AEO + ((q << 2) + r) * 776u + ce) = f2fp8(e_);
                }
            }
        }
        __syncthreads();            // e complete before next step's phase A
    }
#undef ISS2
#undef ISSA
#undef ISSB
#undef ISSC
#undef CONSA
#undef CONSB
#undef CONSC
}

extern "C" void kernel_launch(void* const* d_in, const int* in_sizes, int n_in,
                              void* d_out, int out_size, void* d_ws, size_t ws_size,
                              hipStream_t stream) {
    const float* x     = (const float*)d_in[0];
    const float* gum   = (const float*)d_in[1];
    const float* W_ih  = (const float*)d_in[2];
    const float* W_hh  = (const float*)d_in[3];
    const float* b_ih  = (const float*)d_in[4];
    const float* b_hh  = (const float*)d_in[5];
    const float* W_out = (const float*)d_in[6];
    const float* b_out = (const float*)d_in[7];
    const float* W_emb = (const float*)d_in[8];
    const float* b_emb = (const float*)d_in[9];
    const float* sos   = (const float*)d_in[10];
    float* out = (float*)d_out;

    char* ws = (char*)d_ws;
    u8*    w1f = (u8*)(ws);                    // 1,572,864 B (fp8)
    u8*    wof = (u8*)(ws + 1572864);          //   524,288 B (fp8)
    u8*    wef = (u8*)(ws + 2097152);          //   262,144 B (fp8)
    float* b1  = (float*)(ws + 2359296);       //     8,192 B

    hipFuncSetAttribute((const void*)lstm_fused,
                        hipFuncAttributeMaxDynamicSharedMemorySize, LDS_TOTAL);

    prep<<<9224, 256, 0, stream>>>(W_ih, W_hh, b_ih, b_hh, W_out, W_emb,
                                   w1f, wof, wef, b1);
    lstm_fused<<<128, 512, LDS_TOTAL, stream>>>(x, gum, w1f, wof, wef, b1,
                                                b_out, b_emb, sos, out);
}

// Round 11
// 962.208 us; speedup vs baseline: 4.6753x; 1.2567x over previous
//
#include <hip/hip_runtime.h>
#include <hip/hip_bf16.h>

#define B_   2048
#define V_   1024
#define H_   512
#define E_   256
#define L_   32

typedef __attribute__((ext_vector_type(4))) float f32x4;
typedef unsigned short u16;
typedef unsigned int   u32;
typedef unsigned char  u8;
typedef unsigned long long u64;
typedef long long      i64;

__device__ __forceinline__ u32 f32b(float x){ union{float f;u32 u;}v; v.f=x; return v.u; }
__device__ __forceinline__ float bf32(u32 u){ union{float f;u32 u;}v; v.u=u; return v.f; }
__device__ __forceinline__ u16 f2bf(float x) {
    u32 u = f32b(x);
    u32 r = u + 0x7fffu + ((u >> 16) & 1u);
    return (u16)(r >> 16);
}
// OCP e4m3fn encode, RNE, flush below 2^-6
__device__ __forceinline__ u8 f2e4m3(float x) {
    u32 u = f32b(x);
    u32 s = (u >> 24) & 0x80u;
    u32 a = u & 0x7fffffffu;
    if (a < 0x3c800000u) return (u8)s;
    if (a > 0x43e00000u) a = 0x43e00000u;
    u32 r = a + 0x000fffffu + ((a >> 20) & 1u);
    if (r > 0x43e00000u) r = 0x43e00000u;
    u32 ex = (r >> 23) - 120u;
    u32 mn = (r >> 20) & 7u;
    return (u8)(s | (ex << 3) | mn);
}
__device__ __forceinline__ u8 f2fp8(float x) {
#if __has_builtin(__builtin_amdgcn_cvt_pk_fp8_f32)
    return (u8)(__builtin_amdgcn_cvt_pk_fp8_f32(x, x, 0, false) & 0xff);
#else
    return f2e4m3(x);
#endif
}
__device__ __forceinline__ float sig_(float x)  { return 1.f / (1.f + __expf(-x)); }
__device__ __forceinline__ float tanh_(float x) { return 1.f - 2.f / (__expf(2.f * x) + 1.f); }

// agent-scope relaxed atomics (cache-bypassing; leave L2 weight set intact)
__device__ __forceinline__ void ag_st64(void* p, u64 v) {
    __hip_atomic_store((u64*)p, v, __ATOMIC_RELAXED, __HIP_MEMORY_SCOPE_AGENT);
}
__device__ __forceinline__ u64 ag_ld64(const void* p) {
    return __hip_atomic_load((const u64*)p, __ATOMIC_RELAXED, __HIP_MEMORY_SCOPE_AGENT);
}
__device__ __forceinline__ void ag_st32(void* p, u32 v) {
    __hip_atomic_store((u32*)p, v, __ATOMIC_RELAXED, __HIP_MEMORY_SCOPE_AGENT);
}
__device__ __forceinline__ u32 ag_ld32(const void* p) {
    return __hip_atomic_load((const u32*)p, __ATOMIC_RELAXED, __HIP_MEMORY_SCOPE_AGENT);
}

// -------------------------------------------------------------------------
// Pair-split layouts, all fp8 e4m3 x64. Chunk = 8 KB = 8 waves x 1 KB;
// wave's 1 KB = 2 frags x 512 B. Block hb of a pair owns:
//  w1f[hb]: gates for j in [hb*256, hb*256+256): [hb 2][ks 24][g 4][wv 8][jj 2][l 64][e 8]
//      k = ks*32+(l>>4)*8+e,  row = g*512 + hb*256 + wv*32 + jj*16 + (l&15)
//  wof[hb]: logits v in [hb*512, +512): [hb 2][ks 16][vh2 2][wv 8][jj 2][l 64][e 8]
//      k = ks*32+(l>>4)*8+e,  v = hb*512 + vh2*256 + wv*32 + jj*16 + (l&15)
//  wef[hb]: K-half (vocab) [hb*512,+512): [hb 2][ksp 16][wv 8][jj 2][l 64][e 8]
//      kv = hb*512 + ksp*32+(l>>4)*8+e,  ce = wv*32 + jj*16 + (l&15)
//  b1 = b_ih + b_hh (fp32); then 4096 u32 pair-barrier flags (zeroed here
//  every run -> graph replays re-arm the barriers).
// -------------------------------------------------------------------------
__global__ void prep(const float* __restrict__ W_ih, const float* __restrict__ W_hh,
                     const float* __restrict__ b_ih, const float* __restrict__ b_hh,
                     const float* __restrict__ W_out, const float* __restrict__ W_emb,
                     u8* __restrict__ w1f, u8* __restrict__ wof, u8* __restrict__ wef,
                     float* __restrict__ b1, u32* __restrict__ flg)
{
    int idx = blockIdx.x * 256 + threadIdx.x;
    if (idx < 1572864) {                       // W1-halves -> fp8*64
        int e = idx & 7, l = (idx >> 3) & 63, jj = (idx >> 9) & 1, wv = (idx >> 10) & 7,
            g = (idx >> 13) & 3;
        int rest = idx >> 15;                  // [0,48)
        int hb = rest / 24, ks = rest % 24;
        int k = ks * 32 + ((l >> 4) << 3) + e;
        int row = g * 512 + hb * 256 + wv * 32 + jj * 16 + (l & 15);
        float v = (k < E_) ? W_ih[row * E_ + k] : W_hh[row * H_ + (k - E_)];
        w1f[idx] = f2e4m3(v * 64.f);
    } else if (idx < 2097152) {                // W_out-halves -> fp8*64
        int j = idx - 1572864;
        int e = j & 7, l = (j >> 3) & 63, jj = (j >> 9) & 1, wv = (j >> 10) & 7,
            vh2 = (j >> 13) & 1, ks = (j >> 14) & 15, hb = j >> 18;
        int k = ks * 32 + ((l >> 4) << 3) + e;
        int v = hb * 512 + vh2 * 256 + wv * 32 + jj * 16 + (l & 15);
        wof[j] = f2e4m3(W_out[v * H_ + k] * 64.f);
    } else if (idx < 2359296) {                // W_emb K-halves -> fp8*64
        int j = idx - 2097152;
        int e = j & 7, l = (j >> 3) & 63, jj = (j >> 9) & 1, wv = (j >> 10) & 7,
            ksp = (j >> 13) & 15, hb = j >> 17;
        int kv = hb * 512 + ksp * 32 + ((l >> 4) << 3) + e;
        int ce = wv * 32 + jj * 16 + (l & 15);
        wef[j] = f2e4m3(W_emb[ce * V_ + kv] * 64.f);
    } else if (idx < 2361344) {
        int j = idx - 2359296;
        b1[j] = b_ih[j] + b_hh[j];
    } else if (idx < 2365440) {
        flg[idx - 2361344] = 0u;               // re-arm pair barriers each run
    }
}

// LDS layout (bytes)
#define AEO   131072u   // 16 x 776 fp8: [0,256) e*16, [256,768) h*16 (full)
#define XSO   143488u   // 16 x 520 fp8 xs-half = exp(z-m)*256
#define RMX   151808u   // 16x8 f32 row-max partials
#define RSM   152320u   // 16x8 f32 row-sum partials
#define LDS_TOTAL 152832  // ring 16 x 8192 + above

#define WAITVM_(N) asm volatile("s_waitcnt vmcnt(" #N ")" ::: "memory")
#define WAITVM(N) WAITVM_(N)

typedef const __attribute__((address_space(1))) void* gvp;
typedef __attribute__((address_space(3))) void* svp;

__device__ __forceinline__ void pbar(u32* myf, u32* pef, u32 n, u32 tid) {
    asm volatile("s_waitcnt vmcnt(0)" ::: "memory");   // all data stores acked
    __syncthreads();
    if (tid == 0) {
        __hip_atomic_fetch_add(myf, 1u, __ATOMIC_RELAXED, __HIP_MEMORY_SCOPE_AGENT);
        while (__hip_atomic_load(pef, __ATOMIC_RELAXED, __HIP_MEMORY_SCOPE_AGENT) < n)
            __builtin_amdgcn_s_sleep(2);
    }
    __syncthreads();
}

__global__ __launch_bounds__(512, 2)
void lstm_fused(const float* __restrict__ x, const float* __restrict__ gum,
                const u8* __restrict__ w1f, const u8* __restrict__ wof,
                const u8* __restrict__ wef, const float* __restrict__ b1,
                const float* __restrict__ b_out, const float* __restrict__ b_emb,
                const float* __restrict__ sos, float* __restrict__ out,
                u8* __restrict__ hx, char* __restrict__ ms, char* __restrict__ ep,
                u32* __restrict__ flg)
{
    extern __shared__ char smem[];

    const u32 tid = threadIdx.x;
    const u32 w   = tid >> 6;        // wave 0..7
    const u32 l   = tid & 63u;
    const u32 q   = l >> 4;
    const u32 col = l & 15u;

    const u32 bid = blockIdx.x;
    const u32 p   = bid & 127u;      // pair id (rows)
    const u32 hb  = bid >> 7;        // half: pairs (i, i+128) share an XCD
    const u32 ph  = 1u - hb;
    const int r0  = (int)(p << 4);

    u32* myf = flg + p * 32u + hb * 16u;
    u32* pef = flg + p * 32u + ph * 16u;
    u32 nbar = 0;

    const u32 wK  = w << 10;         // wave's 1 KB slice inside a chunk
    const u32 lB  = l << 4;
    const u32 l8  = l << 3;
    const u32 q8  = q << 3;
    const u32 colB776 = col * 776u;
    const u32 colB520 = col * 520u;

    const char* w1p = (const char*)w1f + (size_t)hb * 786432u;
    const char* wop = (const char*)wof + (size_t)hb * 262144u;
    const char* wep = (const char*)wef + (size_t)hb * 131072u;

#define ISS(BASE, C) do { u32 _c = (u32)(C); \
    u32 _o = (u32)__builtin_amdgcn_readfirstlane((int)(((_c & 15u) << 13) + wK)); \
    __builtin_amdgcn_global_load_lds((gvp)((BASE) + ((size_t)_c << 13) + wK + lB), \
                                     (svp)(smem + _o), 16, 0, 0); } while (0)

#define CONSA(G, C) { const char* _fb = smem + (((u32)(C) & 15u) << 13) + wK + l8; \
    acc[G][0] = __builtin_amdgcn_mfma_f32_16x16x32_fp8_fp8(a8, *(const i64*)(_fb), acc[G][0], 0, 0, 0); \
    acc[G][1] = __builtin_amdgcn_mfma_f32_16x16x32_fp8_fp8(a8, *(const i64*)(_fb + 512u), acc[G][1], 0, 0, 0); }

#define CONSB(V2, C, A8) { const char* _fb = smem + (((u32)(C) & 15u) << 13) + wK + l8; \
    accB[V2][0] = __builtin_amdgcn_mfma_f32_16x16x32_fp8_fp8(A8, *(const i64*)(_fb), accB[V2][0], 0, 0, 0); \
    accB[V2][1] = __builtin_amdgcn_mfma_f32_16x16x32_fp8_fp8(A8, *(const i64*)(_fb + 512u), accB[V2][1], 0, 0, 0); }

#define CONSC(C) { const char* _fb = smem + (((u32)(C) & 15u) << 13) + wK + l8; \
    i64 _x = *(const i64*)(smem + XSO + colB520 + (((u32)(C)) << 5) + q8); \
    accC[0] = __builtin_amdgcn_mfma_f32_16x16x32_fp8_fp8(_x, *(const i64*)(_fb), accC[0], 0, 0, 0); \
    accC[1] = __builtin_amdgcn_mfma_f32_16x16x32_fp8_fp8(_x, *(const i64*)(_fb + 512u), accC[1], 0, 0, 0); }

    // EOS v-half
    for (u32 i = tid; i < 16u * 512u; i += 512u) {
        u32 row = i >> 9, vl = i & 511u;
        __builtin_nontemporal_store((hb == 0u && vl == 0u) ? 1.f : 0.f,
            &out[((size_t)(r0 + (int)row) * 33 + 32) * V_ + hb * 512u + vl]);
    }
    // e0 = sos*16 (full), h0 = x*16 (full)
    for (u32 i = tid; i < 16u * 256u; i += 512u) {
        u32 row = i >> 8, k = i & 255u;
        *(u8*)(smem + AEO + row * 776u + k) = f2fp8(sos[k] * 16.f);
    }
    for (u32 i = tid; i < 16u * 512u; i += 512u) {
        u32 row = i >> 9, k = i & 511u;
        *(u8*)(smem + AEO + row * 776u + 256u + k) = f2fp8(x[(r0 + (int)row) * H_ + k] * 16.f);
    }

    // biases (own halves)
    float bia[2], bfa[2], bga[2], boa[2];
    #pragma unroll
    for (int jj = 0; jj < 2; ++jj) {
        int jg = (int)(hb * 256u + (w << 5) + ((u32)jj << 4) + col);
        bia[jj] = b1[jg];           bfa[jj] = b1[H_ + jg];
        bga[jj] = b1[2 * H_ + jg];  boa[jj] = b1[3 * H_ + jg];
    }
    float bov[2][2];
    #pragma unroll
    for (int v2 = 0; v2 < 2; ++v2)
        #pragma unroll
        for (int jj = 0; jj < 2; ++jj)
            bov[v2][jj] = b_out[hb * 512u + (u32)v2 * 256u + (w << 5) + ((u32)jj << 4) + col];
    float bem16[2];
    #pragma unroll
    for (int jj = 0; jj < 2; ++jj)
        bem16[jj] = b_emb[(w << 5) + ((u32)jj << 4) + col] * 16.f;

    float creg[2][4];
    #pragma unroll
    for (int jj = 0; jj < 2; ++jj)
        #pragma unroll
        for (int r = 0; r < 4; ++r) creg[jj][r] = 0.f;

    __syncthreads();

    const f32x4 fz = {0.f, 0.f, 0.f, 0.f};
    const float S1 = 1.f / 1024.f;

    #pragma unroll 1
    for (int t = 0; t < L_; ++t) {
        // ====== phase A: gate-half, ring-16 of 8 KB chunks (96) ======
        f32x4 acc[4][2];
        #pragma unroll
        for (int g = 0; g < 4; ++g) { acc[g][0] = fz; acc[g][1] = fz; }

        ISS(w1p, 0);  ISS(w1p, 1);  ISS(w1p, 2);  ISS(w1p, 3);  ISS(w1p, 4);
        ISS(w1p, 5);  ISS(w1p, 6);  ISS(w1p, 7);  ISS(w1p, 8);  ISS(w1p, 9);
        ISS(w1p, 10); ISS(w1p, 11); ISS(w1p, 12); ISS(w1p, 13); ISS(w1p, 14);
        #pragma unroll 1
        for (int ks = 0; ks < 20; ++ks) {
            i64 a8 = *(const i64*)(smem + AEO + colB776 + ((u32)ks << 5) + q8);
            int c0 = ks << 2;
            WAITVM(11);
            CONSA(0, c0); CONSA(1, c0 + 1); CONSA(2, c0 + 2); CONSA(3, c0 + 3);
            ISS(w1p, c0 + 15); ISS(w1p, c0 + 16); ISS(w1p, c0 + 17); ISS(w1p, c0 + 18);
        }
        {   i64 a8 = *(const i64*)(smem + AEO + colB776 + (20u << 5) + q8);
            WAITVM(11); CONSA(0, 80); CONSA(1, 81); CONSA(2, 82); CONSA(3, 83); ISS(w1p, 95); }
        {   i64 a8 = *(const i64*)(smem + AEO + colB776 + (21u << 5) + q8);
            WAITVM(8);  CONSA(0, 84); CONSA(1, 85); CONSA(2, 86); CONSA(3, 87); }
        {   i64 a8 = *(const i64*)(smem + AEO + colB776 + (22u << 5) + q8);
            WAITVM(4);  CONSA(0, 88); CONSA(1, 89); CONSA(2, 90); CONSA(3, 91); }
        {   i64 a8 = *(const i64*)(smem + AEO + colB776 + (23u << 5) + q8);
            WAITVM(0);  CONSA(0, 92); CONSA(1, 93); CONSA(2, 94); CONSA(3, 95); }
        __syncthreads();            // AEO reads done before h overwrite

        // LSTM pointwise (own j-half)
        #pragma unroll
        for (int jj = 0; jj < 2; ++jj) {
            u32 jg = hb * 256u + (w << 5) + ((u32)jj << 4) + col;
            #pragma unroll
            for (int r = 0; r < 4; ++r) {
                float gi = sig_(acc[0][jj][r] * S1 + bia[jj]);
                float gf = sig_(acc[1][jj][r] * S1 + bfa[jj]);
                float gg = tanh_(acc[2][jj][r] * S1 + bga[jj]);
                float go = sig_(acc[3][jj][r] * S1 + boa[jj]);
                float c  = gf * creg[jj][r] + gi * gg;
                creg[jj][r] = c;
                float h = go * tanh_(c);
                *(u8*)(smem + AEO + ((q << 2) + (u32)r) * 776u + 256u + jg) = f2fp8(h * 16.f);
            }
        }
        __syncthreads();            // own h-half complete in AEO

        // export own h-half (coalesced u64, agent atomics)
        {   u32 row = tid >> 5, off = (tid & 31u) << 3;
            u64 v = *(const u64*)(smem + AEO + row * 776u + 256u + hb * 256u + off);
            ag_st64(hx + (size_t)p * 8192u + row * 512u + hb * 256u + off, v);
        }
        ++nbar; pbar(myf, pef, nbar, tid);     // barrier 1: h ready
        {   u32 row = tid >> 5, off = (tid & 31u) << 3;
            u64 v = ag_ld64(hx + (size_t)p * 8192u + row * 512u + ph * 256u + off);
            *(u64*)(smem + AEO + row * 776u + 256u + ph * 256u + off) = v;
        }
        __syncthreads();            // full h in AEO

        // ====== phase B: logit v-half, ring-16 (32 chunks) ======
        const float* gt = gum + (size_t)t * (B_ * V_) + (size_t)r0 * V_;
        float gr[2][2][4];
        #pragma unroll
        for (int v2 = 0; v2 < 2; ++v2)
            #pragma unroll
            for (int jj = 0; jj < 2; ++jj) {
                u32 vg = hb * 512u + (u32)v2 * 256u + (w << 5) + ((u32)jj << 4) + col;
                #pragma unroll
                for (int r = 0; r < 4; ++r)
                    gr[v2][jj][r] = __builtin_nontemporal_load(&gt[((q << 2) + (u32)r) * V_ + vg]);
            }

        f32x4 accB[2][2];
        accB[0][0] = fz; accB[0][1] = fz; accB[1][0] = fz; accB[1][1] = fz;
        ISS(wop, 0);  ISS(wop, 1);  ISS(wop, 2);  ISS(wop, 3);  ISS(wop, 4);
        ISS(wop, 5);  ISS(wop, 6);  ISS(wop, 7);  ISS(wop, 8);  ISS(wop, 9);
        ISS(wop, 10); ISS(wop, 11); ISS(wop, 12); ISS(wop, 13); ISS(wop, 14);
        #pragma unroll 1
        for (int g = 0; g < 4; ++g) {
            i64 a80 = *(const i64*)(smem + AEO + colB776 + 256u + (((u32)g << 1) << 5) + q8);
            i64 a81 = *(const i64*)(smem + AEO + colB776 + 256u + ((((u32)g << 1) | 1u) << 5) + q8);
            int c0 = g << 2;
            WAITVM(11);
            CONSB(0, c0, a80); CONSB(1, c0 + 1, a80);
            CONSB(0, c0 + 2, a81); CONSB(1, c0 + 3, a81);
            ISS(wop, c0 + 15); ISS(wop, c0 + 16); ISS(wop, c0 + 17); ISS(wop, c0 + 18);
        }
        {   i64 a80 = *(const i64*)(smem + AEO + colB776 + 256u + (8u << 5) + q8);
            i64 a81 = *(const i64*)(smem + AEO + colB776 + 256u + (9u << 5) + q8);
            WAITVM(11); CONSB(0, 16, a80); CONSB(1, 17, a80); CONSB(0, 18, a81); CONSB(1, 19, a81);
            ISS(wop, 31); }
        {   i64 a80 = *(const i64*)(smem + AEO + colB776 + 256u + (10u << 5) + q8);
            i64 a81 = *(const i64*)(smem + AEO + colB776 + 256u + (11u << 5) + q8);
            WAITVM(8);  CONSB(0, 20, a80); CONSB(1, 21, a80); CONSB(0, 22, a81); CONSB(1, 23, a81); }
        {   i64 a80 = *(const i64*)(smem + AEO + colB776 + 256u + (12u << 5) + q8);
            i64 a81 = *(const i64*)(smem + AEO + colB776 + 256u + (13u << 5) + q8);
            WAITVM(4);  CONSB(0, 24, a80); CONSB(1, 25, a80); CONSB(0, 26, a81); CONSB(1, 27, a81); }
        {   i64 a80 = *(const i64*)(smem + AEO + colB776 + 256u + (14u << 5) + q8);
            i64 a81 = *(const i64*)(smem + AEO + colB776 + 256u + (15u << 5) + q8);
            WAITVM(0);  CONSB(0, 28, a80); CONSB(1, 29, a80); CONSB(0, 30, a81); CONSB(1, 31, a81); }

        // z; local (half) max
        float m_loc[4], s_loc[4];
        #pragma unroll
        for (int r = 0; r < 4; ++r) m_loc[r] = -1e30f;
        #pragma unroll
        for (int v2 = 0; v2 < 2; ++v2)
            #pragma unroll
            for (int jj = 0; jj < 2; ++jj)
                #pragma unroll
                for (int r = 0; r < 4; ++r) {
                    float zz = accB[v2][jj][r] * S1 + bov[v2][jj] + gr[v2][jj][r];
                    accB[v2][jj][r] = zz;
                    m_loc[r] = fmaxf(m_loc[r], zz);
                }
        #pragma unroll
        for (int m = 1; m < 16; m <<= 1)
            #pragma unroll
            for (int r = 0; r < 4; ++r) m_loc[r] = fmaxf(m_loc[r], __shfl_xor(m_loc[r], m, 64));
        if (col == 0) {
            #pragma unroll
            for (int r = 0; r < 4; ++r)
                *(float*)(smem + RMX + ((((q << 2) + (u32)r) << 3) + w) * 4u) = m_loc[r];
        }
        __syncthreads();
        #pragma unroll
        for (int r = 0; r < 4; ++r) {
            float mm = -1e30f;
            #pragma unroll
            for (int ww = 0; ww < 8; ++ww)
                mm = fmaxf(mm, *(const float*)(smem + RMX + ((((q << 2) + (u32)r) << 3) + (u32)ww) * 4u));
            m_loc[r] = mm;
        }
        // eb = exp(z - m_loc); local sum
        float ps[4] = {0.f, 0.f, 0.f, 0.f};
        #pragma unroll
        for (int v2 = 0; v2 < 2; ++v2)
            #pragma unroll
            for (int jj = 0; jj < 2; ++jj)
                #pragma unroll
                for (int r = 0; r < 4; ++r) {
                    float Ee = __expf(accB[v2][jj][r] - m_loc[r]);
                    accB[v2][jj][r] = Ee;
                    ps[r] += Ee;
                }
        #pragma unroll
        for (int m = 1; m < 16; m <<= 1)
            #pragma unroll
            for (int r = 0; r < 4; ++r) ps[r] += __shfl_xor(ps[r], m, 64);
        if (col == 0) {
            #pragma unroll
            for (int r = 0; r < 4; ++r)
                *(float*)(smem + RSM + ((((q << 2) + (u32)r) << 3) + w) * 4u) = ps[r];
        }
        __syncthreads();
        #pragma unroll
        for (int r = 0; r < 4; ++r) {
            float ss = 0.f;
            #pragma unroll
            for (int ww = 0; ww < 8; ++ww)
                ss += *(const float*)(smem + RSM + ((((q << 2) + (u32)r) << 3) + (u32)ww) * 4u);
            s_loc[r] = ss;
        }
        // exchange (m,s) with peer half
        if (w == 0 && col == 0) {
            #pragma unroll
            for (int r = 0; r < 4; ++r) {
                u64 v = ((u64)f32b(s_loc[r]) << 32) | (u64)f32b(m_loc[r]);
                ag_st64(ms + (size_t)p * 256u + hb * 128u + (((q << 2) + (u32)r) << 3), v);
            }
        }
        ++nbar; pbar(myf, pef, nbar, tid);     // barrier 2: (m,s) ready
        float fc[4], invs[4];
        #pragma unroll
        for (int r = 0; r < 4; ++r) {
            u64 v = ag_ld64(ms + (size_t)p * 256u + ph * 128u + (((q << 2) + (u32)r) << 3));
            float m_p = bf32((u32)v), s_p = bf32((u32)(v >> 32));
            float mg = fmaxf(m_loc[r], m_p);
            float f0 = __expf(m_loc[r] - mg);
            float s  = s_loc[r] * f0 + s_p * __expf(m_p - mg);
            fc[r] = f0; invs[r] = 1.f / s;
        }
        // xs-half (local), out v-half
        #pragma unroll
        for (int v2 = 0; v2 < 2; ++v2)
            #pragma unroll
            for (int jj = 0; jj < 2; ++jj) {
                u32 vl = (u32)v2 * 256u + (w << 5) + ((u32)jj << 4) + col;
                u32 vg = hb * 512u + vl;
                #pragma unroll
                for (int r = 0; r < 4; ++r) {
                    float Ee = accB[v2][jj][r] * fc[r];
                    *(u8*)(smem + XSO + ((q << 2) + (u32)r) * 520u + vl) = f2fp8(Ee * 256.f);
                    __builtin_nontemporal_store(Ee * invs[r],
                        &out[((size_t)(r0 + (int)((q << 2) + (u32)r)) * 33 + t) * V_ + vg]);
                }
            }
        __syncthreads();            // xs-half visible block-wide

        // ====== phase C: partial e (own K-half), ring-16 (16 chunks) ======
        f32x4 accC[2];
        accC[0] = fz; accC[1] = fz;
        ISS(wep, 0);  ISS(wep, 1);  ISS(wep, 2);  ISS(wep, 3);  ISS(wep, 4);
        ISS(wep, 5);  ISS(wep, 6);  ISS(wep, 7);  ISS(wep, 8);  ISS(wep, 9);
        ISS(wep, 10); ISS(wep, 11); ISS(wep, 12); ISS(wep, 13); ISS(wep, 14);
        WAITVM(11); CONSC(0);  CONSC(1);  CONSC(2);  CONSC(3);  ISS(wep, 15);
        WAITVM(8);  CONSC(4);  CONSC(5);  CONSC(6);  CONSC(7);
        WAITVM(4);  CONSC(8);  CONSC(9);  CONSC(10); CONSC(11);
        WAITVM(0);  CONSC(12); CONSC(13); CONSC(14); CONSC(15);

        // partial e -> exchange (bf16), combine, store e to AEO
        float part[2][4];
        #pragma unroll
        for (int jj = 0; jj < 2; ++jj)
            #pragma unroll
            for (int r = 0; r < 4; ++r)
                part[jj][r] = accC[jj][r] * invs[r] * (16.f / 16384.f);
        #pragma unroll
        for (int r = 0; r < 4; ++r) {
            u32 row = (q << 2) + (u32)r;
            u32 pv = (u32)f2bf(part[0][r]) | ((u32)f2bf(part[1][r]) << 16);
            ag_st32(ep + (size_t)p * 16384u + hb * 8192u + (((row << 3) + w) << 6) + (col << 2), pv);
        }
        ++nbar; pbar(myf, pef, nbar, tid);     // barrier 3: e-partials ready
        #pragma unroll
        for (int r = 0; r < 4; ++r) {
            u32 row = (q << 2) + (u32)r;
            u32 pv = ag_ld32(ep + (size_t)p * 16384u + ph * 8192u + (((row << 3) + w) << 6) + (col << 2));
            #pragma unroll
            for (int jj = 0; jj < 2; ++jj) {
                float pe = bf32(((pv >> (16 * jj)) & 0xffffu) << 16);
                float e16 = part[jj][r] + pe + bem16[jj];
                *(u8*)(smem + AEO + row * 776u + (w << 5) + ((u32)jj << 4) + col) = f2fp8(e16);
            }
        }
        __syncthreads();            // e complete before next step's phase A
    }
#undef ISS
#undef CONSA
#undef CONSB
#undef CONSC
}

extern "C" void kernel_launch(void* const* d_in, const int* in_sizes, int n_in,
                              void* d_out, int out_size, void* d_ws, size_t ws_size,
                              hipStream_t stream) {
    const float* x     = (const float*)d_in[0];
    const float* gum   = (const float*)d_in[1];
    const float* W_ih  = (const float*)d_in[2];
    const float* W_hh  = (const float*)d_in[3];
    const float* b_ih  = (const float*)d_in[4];
    const float* b_hh  = (const float*)d_in[5];
    const float* W_out = (const float*)d_in[6];
    const float* b_out = (const float*)d_in[7];
    const float* W_emb = (const float*)d_in[8];
    const float* b_emb = (const float*)d_in[9];
    const float* sos   = (const float*)d_in[10];
    float* out = (float*)d_out;

    char* ws = (char*)d_ws;
    u8*    w1f = (u8*)(ws);                    // 1,572,864 B
    u8*    wof = (u8*)(ws + 1572864);          //   524,288 B
    u8*    wef = (u8*)(ws + 2097152);          //   262,144 B
    float* b1  = (float*)(ws + 2359296);       //     8,192 B
    u32*   flg = (u32*)(ws + 2367488);         //    16,384 B (pair barriers)
    u8*    hx  = (u8*)(ws + 2383872);          // 1,048,576 B (h exchange)
    char*  ms  = (char*)(ws + 3432448);        //    32,768 B (max/sum)
    char*  ep  = (char*)(ws + 3465216);        // 2,097,152 B (e partials)
    // total 5,562,368 B

    hipFuncSetAttribute((const void*)lstm_fused,
                        hipFuncAttributeMaxDynamicSharedMemorySize, LDS_TOTAL);

    prep<<<9240, 256, 0, stream>>>(W_ih, W_hh, b_ih, b_hh, W_out, W_emb,
                                   w1f, wof, wef, b1, flg);
    lstm_fused<<<256, 512, LDS_TOTAL, stream>>>(x, gum, w1f, wof, wef, b1,
                                                b_out, b_emb, sos, out,
                                                hx, ms, ep, flg);
}

// Round 12
// 870.591 us; speedup vs baseline: 5.1673x; 1.1052x over previous
//
#include <hip/hip_runtime.h>
#include <hip/hip_bf16.h>

#define B_   2048
#define V_   1024
#define H_   512
#define E_   256
#define L_   32

typedef __attribute__((ext_vector_type(4))) float f32x4;
typedef unsigned short u16;
typedef unsigned int   u32;
typedef unsigned char  u8;
typedef unsigned long long u64;
typedef long long      i64;

__device__ __forceinline__ u32 f32b(float x){ union{float f;u32 u;}v; v.f=x; return v.u; }
__device__ __forceinline__ float bf32(u32 u){ union{float f;u32 u;}v; v.u=u; return v.f; }
__device__ __forceinline__ u16 f2bf(float x) {
    u32 u = f32b(x);
    u32 r = u + 0x7fffu + ((u >> 16) & 1u);
    return (u16)(r >> 16);
}
// OCP e4m3fn encode, RNE, flush below 2^-6
__device__ __forceinline__ u8 f2e4m3(float x) {
    u32 u = f32b(x);
    u32 s = (u >> 24) & 0x80u;
    u32 a = u & 0x7fffffffu;
    if (a < 0x3c800000u) return (u8)s;
    if (a > 0x43e00000u) a = 0x43e00000u;
    u32 r = a + 0x000fffffu + ((a >> 20) & 1u);
    if (r > 0x43e00000u) r = 0x43e00000u;
    u32 ex = (r >> 23) - 120u;
    u32 mn = (r >> 20) & 7u;
    return (u8)(s | (ex << 3) | mn);
}
__device__ __forceinline__ u8 f2fp8(float x) {
#if __has_builtin(__builtin_amdgcn_cvt_pk_fp8_f32)
    return (u8)(__builtin_amdgcn_cvt_pk_fp8_f32(x, x, 0, false) & 0xff);
#else
    return f2e4m3(x);
#endif
}
__device__ __forceinline__ float sig_(float x)  { return 1.f / (1.f + __expf(-x)); }
__device__ __forceinline__ float tanh_(float x) { return 1.f - 2.f / (__expf(2.f * x) + 1.f); }

// agent-scope relaxed atomics (device-coherent; pair lives on same XCD L2)
__device__ __forceinline__ void ag_st64(void* p, u64 v) {
    __hip_atomic_store((u64*)p, v, __ATOMIC_RELAXED, __HIP_MEMORY_SCOPE_AGENT);
}
__device__ __forceinline__ u64 ag_ld64(const void* p) {
    return __hip_atomic_load((const u64*)p, __ATOMIC_RELAXED, __HIP_MEMORY_SCOPE_AGENT);
}
__device__ __forceinline__ void ag_st32(void* p, u32 v) {
    __hip_atomic_store((u32*)p, v, __ATOMIC_RELAXED, __HIP_MEMORY_SCOPE_AGENT);
}
__device__ __forceinline__ u32 ag_ld32(const void* p) {
    return __hip_atomic_load((const u32*)p, __ATOMIC_RELAXED, __HIP_MEMORY_SCOPE_AGENT);
}

// -------------------------------------------------------------------------
// Pair-split layouts (identical to r11), all fp8 e4m3 x64.
// Chunk = 8 KB = 8 waves x 1 KB; wave's 1 KB = 2 frags x 512 B.
// -------------------------------------------------------------------------
__global__ void prep(const float* __restrict__ W_ih, const float* __restrict__ W_hh,
                     const float* __restrict__ b_ih, const float* __restrict__ b_hh,
                     const float* __restrict__ W_out, const float* __restrict__ W_emb,
                     u8* __restrict__ w1f, u8* __restrict__ wof, u8* __restrict__ wef,
                     float* __restrict__ b1, u32* __restrict__ flg)
{
    int idx = blockIdx.x * 256 + threadIdx.x;
    if (idx < 1572864) {                       // W1-halves -> fp8*64
        int e = idx & 7, l = (idx >> 3) & 63, jj = (idx >> 9) & 1, wv = (idx >> 10) & 7,
            g = (idx >> 13) & 3;
        int rest = idx >> 15;                  // [0,48)
        int hb = rest / 24, ks = rest % 24;
        int k = ks * 32 + ((l >> 4) << 3) + e;
        int row = g * 512 + hb * 256 + wv * 32 + jj * 16 + (l & 15);
        float v = (k < E_) ? W_ih[row * E_ + k] : W_hh[row * H_ + (k - E_)];
        w1f[idx] = f2e4m3(v * 64.f);
    } else if (idx < 2097152) {                // W_out-halves -> fp8*64
        int j = idx - 1572864;
        int e = j & 7, l = (j >> 3) & 63, jj = (j >> 9) & 1, wv = (j >> 10) & 7,
            vh2 = (j >> 13) & 1, ks = (j >> 14) & 15, hb = j >> 18;
        int k = ks * 32 + ((l >> 4) << 3) + e;
        int v = hb * 512 + vh2 * 256 + wv * 32 + jj * 16 + (l & 15);
        wof[j] = f2e4m3(W_out[v * H_ + k] * 64.f);
    } else if (idx < 2359296) {                // W_emb K-halves -> fp8*64
        int j = idx - 2097152;
        int e = j & 7, l = (j >> 3) & 63, jj = (j >> 9) & 1, wv = (j >> 10) & 7,
            ksp = (j >> 13) & 15, hb = j >> 17;
        int kv = hb * 512 + ksp * 32 + ((l >> 4) << 3) + e;
        int ce = wv * 32 + jj * 16 + (l & 15);
        wef[j] = f2e4m3(W_emb[ce * V_ + kv] * 64.f);
    } else if (idx < 2361344) {
        int j = idx - 2359296;
        b1[j] = b_ih[j] + b_hh[j];
    } else if (idx < 2365440) {
        flg[idx - 2361344] = 0u;               // re-arm pair barriers each run
    }
}

// LDS layout (bytes)
#define AEO   131072u   // 16 x 776 fp8: [0,256) e*16, [256,768) h*16 (full)
#define XSO   143488u   // 16 x 520 fp8 xs-half = exp(z-m_loc)*256
#define RMX   151808u   // 16x8 f32 row-max partials
#define RSM   152320u   // 16x8 f32 row-sum partials
#define LDS_TOTAL 152832  // ring 16 x 8192 + above

#define WAITVM_(N) asm volatile("s_waitcnt vmcnt(" #N ")" ::: "memory")
#define WAITVM(N) WAITVM_(N)

typedef const __attribute__((address_space(1))) void* gvp;
typedef __attribute__((address_space(3))) void* svp;

__device__ __forceinline__ void pbar(u32* myf, u32* pef, u32 n, u32 tid) {
    asm volatile("s_waitcnt vmcnt(0)" ::: "memory");   // all data stores acked
    __syncthreads();
    if (tid == 0) {
        __hip_atomic_fetch_add(myf, 1u, __ATOMIC_RELAXED, __HIP_MEMORY_SCOPE_AGENT);
        while (__hip_atomic_load(pef, __ATOMIC_RELAXED, __HIP_MEMORY_SCOPE_AGENT) < n)
            __builtin_amdgcn_s_sleep(2);
    }
    __syncthreads();
}

__global__ __launch_bounds__(512, 2)
void lstm_fused(const float* __restrict__ x, const float* __restrict__ gum,
                const u8* __restrict__ w1f, const u8* __restrict__ wof,
                const u8* __restrict__ wef, const float* __restrict__ b1,
                const float* __restrict__ b_out, const float* __restrict__ b_emb,
                const float* __restrict__ sos, float* __restrict__ out,
                u8* __restrict__ hx, char* __restrict__ ms, char* __restrict__ ep,
                u32* __restrict__ flg)
{
    extern __shared__ char smem[];

    const u32 tid = threadIdx.x;
    const u32 w   = tid >> 6;        // wave 0..7
    const u32 l   = tid & 63u;
    const u32 q   = l >> 4;
    const u32 col = l & 15u;

    const u32 bid = blockIdx.x;
    const u32 p   = bid & 127u;      // pair id (rows)
    const u32 hb  = bid >> 7;        // half: pairs (i, i+128) share an XCD
    const u32 ph  = 1u - hb;
    const int r0  = (int)(p << 4);

    u32* myf = flg + p * 32u + hb * 16u;
    u32* pef = flg + p * 32u + ph * 16u;
    u32 nbar = 0;

    const u32 wK  = w << 10;         // wave's 1 KB slice inside a chunk
    const u32 lB  = l << 4;
    const u32 l8  = l << 3;
    const u32 q8  = q << 3;
    const u32 colB776 = col * 776u;
    const u32 colB520 = col * 520u;

    const char* w1p = (const char*)w1f + (size_t)hb * 786432u;
    const char* wop = (const char*)wof + (size_t)hb * 262144u;
    const char* wep = (const char*)wef + (size_t)hb * 131072u;

#define ISS(BASE, C) do { u32 _c = (u32)(C); \
    u32 _o = (u32)__builtin_amdgcn_readfirstlane((int)(((_c & 15u) << 13) + wK)); \
    __builtin_amdgcn_global_load_lds((gvp)((BASE) + ((size_t)_c << 13) + wK + lB), \
                                     (svp)(smem + _o), 16, 0, 0); } while (0)

#define CONSA(G, C) { const char* _fb = smem + (((u32)(C) & 15u) << 13) + wK + l8; \
    acc[G][0] = __builtin_amdgcn_mfma_f32_16x16x32_fp8_fp8(a8, *(const i64*)(_fb), acc[G][0], 0, 0, 0); \
    acc[G][1] = __builtin_amdgcn_mfma_f32_16x16x32_fp8_fp8(a8, *(const i64*)(_fb + 512u), acc[G][1], 0, 0, 0); }

#define CONSB(V2, C, A8) { const char* _fb = smem + (((u32)(C) & 15u) << 13) + wK + l8; \
    accB[V2][0] = __builtin_amdgcn_mfma_f32_16x16x32_fp8_fp8(A8, *(const i64*)(_fb), accB[V2][0], 0, 0, 0); \
    accB[V2][1] = __builtin_amdgcn_mfma_f32_16x16x32_fp8_fp8(A8, *(const i64*)(_fb + 512u), accB[V2][1], 0, 0, 0); }

#define CONSC(C) { const char* _fb = smem + (((u32)(C) & 15u) << 13) + wK + l8; \
    i64 _x = *(const i64*)(smem + XSO + colB520 + (((u32)(C)) << 5) + q8); \
    accC[0] = __builtin_amdgcn_mfma_f32_16x16x32_fp8_fp8(_x, *(const i64*)(_fb), accC[0], 0, 0, 0); \
    accC[1] = __builtin_amdgcn_mfma_f32_16x16x32_fp8_fp8(_x, *(const i64*)(_fb + 512u), accC[1], 0, 0, 0); }

    // EOS v-half
    for (u32 i = tid; i < 16u * 512u; i += 512u) {
        u32 row = i >> 9, vl = i & 511u;
        __builtin_nontemporal_store((hb == 0u && vl == 0u) ? 1.f : 0.f,
            &out[((size_t)(r0 + (int)row) * 33 + 32) * V_ + hb * 512u + vl]);
    }
    // e0 = sos*16 (full), h0 = x*16 (full)
    for (u32 i = tid; i < 16u * 256u; i += 512u) {
        u32 row = i >> 8, k = i & 255u;
        *(u8*)(smem + AEO + row * 776u + k) = f2fp8(sos[k] * 16.f);
    }
    for (u32 i = tid; i < 16u * 512u; i += 512u) {
        u32 row = i >> 9, k = i & 511u;
        *(u8*)(smem + AEO + row * 776u + 256u + k) = f2fp8(x[(r0 + (int)row) * H_ + k] * 16.f);
    }

    // biases (own halves)
    float bia[2], bfa[2], bga[2], boa[2];
    #pragma unroll
    for (int jj = 0; jj < 2; ++jj) {
        int jg = (int)(hb * 256u + (w << 5) + ((u32)jj << 4) + col);
        bia[jj] = b1[jg];           bfa[jj] = b1[H_ + jg];
        bga[jj] = b1[2 * H_ + jg];  boa[jj] = b1[3 * H_ + jg];
    }
    float bov[2][2];
    #pragma unroll
    for (int v2 = 0; v2 < 2; ++v2)
        #pragma unroll
        for (int jj = 0; jj < 2; ++jj)
            bov[v2][jj] = b_out[hb * 512u + (u32)v2 * 256u + (w << 5) + ((u32)jj << 4) + col];
    float bem16[2];
    #pragma unroll
    for (int jj = 0; jj < 2; ++jj)
        bem16[jj] = b_emb[(w << 5) + ((u32)jj << 4) + col] * 16.f;

    float creg[2][4];
    #pragma unroll
    for (int jj = 0; jj < 2; ++jj)
        #pragma unroll
        for (int r = 0; r < 4; ++r) creg[jj][r] = 0.f;

    __syncthreads();

    const f32x4 fz = {0.f, 0.f, 0.f, 0.f};
    const float S1 = 1.f / 1024.f;

    // phase-A prologue for t=0 (subsequent steps pre-issue before barrier 2)
    ISS(w1p, 0);  ISS(w1p, 1);  ISS(w1p, 2);  ISS(w1p, 3);  ISS(w1p, 4);
    ISS(w1p, 5);  ISS(w1p, 6);  ISS(w1p, 7);  ISS(w1p, 8);  ISS(w1p, 9);
    ISS(w1p, 10); ISS(w1p, 11); ISS(w1p, 12); ISS(w1p, 13); ISS(w1p, 14);

    #pragma unroll 1
    for (int t = 0; t < L_; ++t) {
        // ====== phase A: gate-half, ring-16 of 8 KB chunks (96) ======
        f32x4 acc[4][2];
        #pragma unroll
        for (int g = 0; g < 4; ++g) { acc[g][0] = fz; acc[g][1] = fz; }

        #pragma unroll 1
        for (int ks = 0; ks < 20; ++ks) {
            i64 a8 = *(const i64*)(smem + AEO + colB776 + ((u32)ks << 5) + q8);
            int c0 = ks << 2;
            WAITVM(11);
            CONSA(0, c0); CONSA(1, c0 + 1); CONSA(2, c0 + 2); CONSA(3, c0 + 3);
            ISS(w1p, c0 + 15); ISS(w1p, c0 + 16); ISS(w1p, c0 + 17); ISS(w1p, c0 + 18);
        }
        {   i64 a8 = *(const i64*)(smem + AEO + colB776 + (20u << 5) + q8);
            WAITVM(11); CONSA(0, 80); CONSA(1, 81); CONSA(2, 82); CONSA(3, 83); ISS(w1p, 95); }
        {   i64 a8 = *(const i64*)(smem + AEO + colB776 + (21u << 5) + q8);
            WAITVM(8);  CONSA(0, 84); CONSA(1, 85); CONSA(2, 86); CONSA(3, 87); }
        {   i64 a8 = *(const i64*)(smem + AEO + colB776 + (22u << 5) + q8);
            WAITVM(4);  CONSA(0, 88); CONSA(1, 89); CONSA(2, 90); CONSA(3, 91); }
        {   i64 a8 = *(const i64*)(smem + AEO + colB776 + (23u << 5) + q8);
            WAITVM(0);  CONSA(0, 92); CONSA(1, 93); CONSA(2, 94); CONSA(3, 95); }
        __syncthreads();            // AEO reads done before h overwrite

        // LSTM pointwise (own j-half)
        #pragma unroll
        for (int jj = 0; jj < 2; ++jj) {
            u32 jg = hb * 256u + (w << 5) + ((u32)jj << 4) + col;
            #pragma unroll
            for (int r = 0; r < 4; ++r) {
                float gi = sig_(acc[0][jj][r] * S1 + bia[jj]);
                float gf = sig_(acc[1][jj][r] * S1 + bfa[jj]);
                float gg = tanh_(acc[2][jj][r] * S1 + bga[jj]);
                float go = sig_(acc[3][jj][r] * S1 + boa[jj]);
                float c  = gf * creg[jj][r] + gi * gg;
                creg[jj][r] = c;
                float h = go * tanh_(c);
                *(u8*)(smem + AEO + ((q << 2) + (u32)r) * 776u + 256u + jg) = f2fp8(h * 16.f);
            }
        }
        __syncthreads();            // own h-half complete in AEO

        // export own h-half; B-prologue + gumbel prefetch hide under barrier 1
        {   u32 row = tid >> 5, off = (tid & 31u) << 3;
            u64 v = *(const u64*)(smem + AEO + row * 776u + 256u + hb * 256u + off);
            ag_st64(hx + (size_t)p * 8192u + row * 512u + hb * 256u + off, v);
        }
        ISS(wop, 0);  ISS(wop, 1);  ISS(wop, 2);  ISS(wop, 3);  ISS(wop, 4);
        ISS(wop, 5);  ISS(wop, 6);  ISS(wop, 7);  ISS(wop, 8);  ISS(wop, 9);
        ISS(wop, 10); ISS(wop, 11); ISS(wop, 12); ISS(wop, 13); ISS(wop, 14);
        const float* gt = gum + (size_t)t * (B_ * V_) + (size_t)r0 * V_;
        float gr[2][2][4];
        #pragma unroll
        for (int v2 = 0; v2 < 2; ++v2)
            #pragma unroll
            for (int jj = 0; jj < 2; ++jj) {
                u32 vg = hb * 512u + (u32)v2 * 256u + (w << 5) + ((u32)jj << 4) + col;
                #pragma unroll
                for (int r = 0; r < 4; ++r)
                    gr[v2][jj][r] = __builtin_nontemporal_load(&gt[((q << 2) + (u32)r) * V_ + vg]);
            }
        ++nbar; pbar(myf, pef, nbar, tid);     // barrier 1: h ready
        {   u32 row = tid >> 5, off = (tid & 31u) << 3;
            u64 v = ag_ld64(hx + (size_t)p * 8192u + row * 512u + ph * 256u + off);
            *(u64*)(smem + AEO + row * 776u + 256u + ph * 256u + off) = v;
        }
        __syncthreads();            // full h in AEO

        // ====== phase B: logit v-half, ring-16 (32 chunks) ======
        f32x4 accB[2][2];
        accB[0][0] = fz; accB[0][1] = fz; accB[1][0] = fz; accB[1][1] = fz;
        #pragma unroll 1
        for (int g = 0; g < 4; ++g) {
            i64 a80 = *(const i64*)(smem + AEO + colB776 + 256u + (((u32)g << 1) << 5) + q8);
            i64 a81 = *(const i64*)(smem + AEO + colB776 + 256u + ((((u32)g << 1) | 1u) << 5) + q8);
            int c0 = g << 2;
            WAITVM(11);
            CONSB(0, c0, a80); CONSB(1, c0 + 1, a80);
            CONSB(0, c0 + 2, a81); CONSB(1, c0 + 3, a81);
            ISS(wop, c0 + 15); ISS(wop, c0 + 16); ISS(wop, c0 + 17); ISS(wop, c0 + 18);
        }
        {   i64 a80 = *(const i64*)(smem + AEO + colB776 + 256u + (8u << 5) + q8);
            i64 a81 = *(const i64*)(smem + AEO + colB776 + 256u + (9u << 5) + q8);
            WAITVM(11); CONSB(0, 16, a80); CONSB(1, 17, a80); CONSB(0, 18, a81); CONSB(1, 19, a81);
            ISS(wop, 31); }
        {   i64 a80 = *(const i64*)(smem + AEO + colB776 + 256u + (10u << 5) + q8);
            i64 a81 = *(const i64*)(smem + AEO + colB776 + 256u + (11u << 5) + q8);
            WAITVM(8);  CONSB(0, 20, a80); CONSB(1, 21, a80); CONSB(0, 22, a81); CONSB(1, 23, a81); }
        {   i64 a80 = *(const i64*)(smem + AEO + colB776 + 256u + (12u << 5) + q8);
            i64 a81 = *(const i64*)(smem + AEO + colB776 + 256u + (13u << 5) + q8);
            WAITVM(4);  CONSB(0, 24, a80); CONSB(1, 25, a80); CONSB(0, 26, a81); CONSB(1, 27, a81); }
        {   i64 a80 = *(const i64*)(smem + AEO + colB776 + 256u + (14u << 5) + q8);
            i64 a81 = *(const i64*)(smem + AEO + colB776 + 256u + (15u << 5) + q8);
            WAITVM(0);  CONSB(0, 28, a80); CONSB(1, 29, a80); CONSB(0, 30, a81); CONSB(1, 31, a81); }

        // z; LOCAL (half) max — no cross-block exchange needed before phase C
        float m_loc[4], s_loc[4];
        #pragma unroll
        for (int r = 0; r < 4; ++r) m_loc[r] = -1e30f;
        #pragma unroll
        for (int v2 = 0; v2 < 2; ++v2)
            #pragma unroll
            for (int jj = 0; jj < 2; ++jj)
                #pragma unroll
                for (int r = 0; r < 4; ++r) {
                    float zz = accB[v2][jj][r] * S1 + bov[v2][jj] + gr[v2][jj][r];
                    accB[v2][jj][r] = zz;
                    m_loc[r] = fmaxf(m_loc[r], zz);
                }
        #pragma unroll
        for (int m = 1; m < 16; m <<= 1)
            #pragma unroll
            for (int r = 0; r < 4; ++r) m_loc[r] = fmaxf(m_loc[r], __shfl_xor(m_loc[r], m, 64));
        if (col == 0) {
            #pragma unroll
            for (int r = 0; r < 4; ++r)
                *(float*)(smem + RMX + ((((q << 2) + (u32)r) << 3) + w) * 4u) = m_loc[r];
        }
        __syncthreads();
        #pragma unroll
        for (int r = 0; r < 4; ++r) {
            float mm = -1e30f;
            #pragma unroll
            for (int ww = 0; ww < 8; ++ww)
                mm = fmaxf(mm, *(const float*)(smem + RMX + ((((q << 2) + (u32)r) << 3) + (u32)ww) * 4u));
            m_loc[r] = mm;
        }
        // C-prologue hides under the rest of softmax
        ISS(wep, 0);  ISS(wep, 1);  ISS(wep, 2);  ISS(wep, 3);  ISS(wep, 4);
        ISS(wep, 5);  ISS(wep, 6);  ISS(wep, 7);  ISS(wep, 8);  ISS(wep, 9);
        ISS(wep, 10); ISS(wep, 11); ISS(wep, 12); ISS(wep, 13); ISS(wep, 14);
        // eb = exp(z - m_loc); local sum; xs-half (local scale)
        float ps[4] = {0.f, 0.f, 0.f, 0.f};
        #pragma unroll
        for (int v2 = 0; v2 < 2; ++v2)
            #pragma unroll
            for (int jj = 0; jj < 2; ++jj) {
                u32 vl = (u32)v2 * 256u + (w << 5) + ((u32)jj << 4) + col;
                #pragma unroll
                for (int r = 0; r < 4; ++r) {
                    float Ee = __expf(accB[v2][jj][r] - m_loc[r]);
                    accB[v2][jj][r] = Ee;
                    ps[r] += Ee;
                    *(u8*)(smem + XSO + ((q << 2) + (u32)r) * 520u + vl) = f2fp8(Ee * 256.f);
                }
            }
        #pragma unroll
        for (int m = 1; m < 16; m <<= 1)
            #pragma unroll
            for (int r = 0; r < 4; ++r) ps[r] += __shfl_xor(ps[r], m, 64);
        if (col == 0) {
            #pragma unroll
            for (int r = 0; r < 4; ++r)
                *(float*)(smem + RSM + ((((q << 2) + (u32)r) << 3) + w) * 4u) = ps[r];
        }
        __syncthreads();            // xs + RSM visible block-wide
        #pragma unroll
        for (int r = 0; r < 4; ++r) {
            float ss = 0.f;
            #pragma unroll
            for (int ww = 0; ww < 8; ++ww)
                ss += *(const float*)(smem + RSM + ((((q << 2) + (u32)r) << 3) + (u32)ww) * 4u);
            s_loc[r] = ss;
        }

        // ====== phase C: partial e (own K-half, LOCAL xs), ring-16 (16) ======
        f32x4 accC[2];
        accC[0] = fz; accC[1] = fz;
        WAITVM(11); CONSC(0);  CONSC(1);  CONSC(2);  CONSC(3);  ISS(wep, 15);
        WAITVM(8);  CONSC(4);  CONSC(5);  CONSC(6);  CONSC(7);
        WAITVM(4);  CONSC(8);  CONSC(9);  CONSC(10); CONSC(11);
        WAITVM(0);  CONSC(12); CONSC(13); CONSC(14); CONSC(15);

        // exchange (m,s) + UNNORMALIZED e-partials in ONE barrier
        float part[2][4];
        #pragma unroll
        for (int jj = 0; jj < 2; ++jj)
            #pragma unroll
            for (int r = 0; r < 4; ++r)
                part[jj][r] = accC[jj][r] * (16.f / 16384.f);   // 16 * sum(eb*W)
        if (w == 0 && col == 0) {
            #pragma unroll
            for (int r = 0; r < 4; ++r) {
                u64 v = ((u64)f32b(s_loc[r]) << 32) | (u64)f32b(m_loc[r]);
                ag_st64(ms + (size_t)p * 256u + hb * 128u + (((q << 2) + (u32)r) << 3), v);
            }
        }
        #pragma unroll
        for (int r = 0; r < 4; ++r) {
            u32 row = (q << 2) + (u32)r;
            u32 pv = (u32)f2bf(part[0][r]) | ((u32)f2bf(part[1][r]) << 16);
            ag_st32(ep + (size_t)p * 16384u + hb * 8192u + (((row << 3) + w) << 6) + (col << 2), pv);
        }
        // next step's A-prologue hides under barrier 2
        ISS(w1p, 0);  ISS(w1p, 1);  ISS(w1p, 2);  ISS(w1p, 3);  ISS(w1p, 4);
        ISS(w1p, 5);  ISS(w1p, 6);  ISS(w1p, 7);  ISS(w1p, 8);  ISS(w1p, 9);
        ISS(w1p, 10); ISS(w1p, 11); ISS(w1p, 12); ISS(w1p, 13); ISS(w1p, 14);
        ++nbar; pbar(myf, pef, nbar, tid);     // barrier 2: (m,s) + partials

        // global softmax factors
        float f0a[4], f1a[4], inva[4];
        #pragma unroll
        for (int r = 0; r < 4; ++r) {
            u64 v = ag_ld64(ms + (size_t)p * 256u + ph * 128u + (((q << 2) + (u32)r) << 3));
            float m_p = bf32((u32)v), s_p = bf32((u32)(v >> 32));
            float mg = fmaxf(m_loc[r], m_p);
            float f0 = __expf(m_loc[r] - mg), f1 = __expf(m_p - mg);
            float inv = 1.f / (s_loc[r] * f0 + s_p * f1);
            f0a[r] = f0; f1a[r] = f1; inva[r] = inv;
        }
        // out v-half (fp32 eb still live in accB)
        #pragma unroll
        for (int v2 = 0; v2 < 2; ++v2)
            #pragma unroll
            for (int jj = 0; jj < 2; ++jj) {
                u32 vg = hb * 512u + (u32)v2 * 256u + (w << 5) + ((u32)jj << 4) + col;
                #pragma unroll
                for (int r = 0; r < 4; ++r)
                    __builtin_nontemporal_store(accB[v2][jj][r] * f0a[r] * inva[r],
                        &out[((size_t)(r0 + (int)((q << 2) + (u32)r)) * 33 + t) * V_ + vg]);
            }
        // combine e-partials -> e
        #pragma unroll
        for (int r = 0; r < 4; ++r) {
            u32 row = (q << 2) + (u32)r;
            u32 pv = ag_ld32(ep + (size_t)p * 16384u + ph * 8192u + (((row << 3) + w) << 6) + (col << 2));
            #pragma unroll
            for (int jj = 0; jj < 2; ++jj) {
                float pe = bf32(((pv >> (16 * jj)) & 0xffffu) << 16);
                float e16 = (part[jj][r] * f0a[r] + pe * f1a[r]) * inva[r] + bem16[jj];
                *(u8*)(smem + AEO + row * 776u + (w << 5) + ((u32)jj << 4) + col) = f2fp8(e16);
            }
        }
        __syncthreads();            // e complete before next step's phase A
    }
#undef ISS
#undef CONSA
#undef CONSB
#undef CONSC
}

extern "C" void kernel_launch(void* const* d_in, const int* in_sizes, int n_in,
                              void* d_out, int out_size, void* d_ws, size_t ws_size,
                              hipStream_t stream) {
    const float* x     = (const float*)d_in[0];
    const float* gum   = (const float*)d_in[1];
    const float* W_ih  = (const float*)d_in[2];
    const float* W_hh  = (const float*)d_in[3];
    const float* b_ih  = (const float*)d_in[4];
    const float* b_hh  = (const float*)d_in[5];
    const float* W_out = (const float*)d_in[6];
    const float* b_out = (const float*)d_in[7];
    const float* W_emb = (const float*)d_in[8];
    const float* b_emb = (const float*)d_in[9];
    const float* sos   = (const float*)d_in[10];
    float* out = (float*)d_out;

    char* ws = (char*)d_ws;
    u8*    w1f = (u8*)(ws);                    // 1,572,864 B
    u8*    wof = (u8*)(ws + 1572864);          //   524,288 B
    u8*    wef = (u8*)(ws + 2097152);          //   262,144 B
    float* b1  = (float*)(ws + 2359296);       //     8,192 B
    u32*   flg = (u32*)(ws + 2367488);         //    16,384 B (pair barriers)
    u8*    hx  = (u8*)(ws + 2383872);          // 1,048,576 B (h exchange)
    char*  ms  = (char*)(ws + 3432448);        //    32,768 B (max/sum)
    char*  ep  = (char*)(ws + 3465216);        // 2,097,152 B (e partials)
    // total 5,562,368 B

    hipFuncSetAttribute((const void*)lstm_fused,
                        hipFuncAttributeMaxDynamicSharedMemorySize, LDS_TOTAL);

    prep<<<9240, 256, 0, stream>>>(W_ih, W_hh, b_ih, b_hh, W_out, W_emb,
                                   w1f, wof, wef, b1, flg);
    lstm_fused<<<256, 512, LDS_TOTAL, stream>>>(x, gum, w1f, wof, wef, b1,
                                                b_out, b_emb, sos, out,
                                                hx, ms, ep, flg);
}